// Round 1
// baseline (684.532 us; speedup 1.0000x reference)
//
#include <hip/hip_runtime.h>

// ---------------------------------------------------------------------------
// GCN 2-layer forward on MI355X.
//  out = Ahat( relu( Ahat (X W1) + b1 ) W2 ) + b2,  Ahat = D^-1/2 (A+I) D^-1/2
// Factored: g = dis .* (X W);  s[i] = g[i] + sum_{e: dst=i} g[src[e]];
//           layer_out[i] = dis[i]*s[i] + b
// ---------------------------------------------------------------------------

constexpr int IN_CH  = 256;
constexpr int HID    = 128;
constexpr int OUT_CH = 64;

// ---------------- CSR build ----------------

__global__ void hist_kernel(const int* __restrict__ dst, int* __restrict__ cnt, int E) {
    int e = blockIdx.x * blockDim.x + threadIdx.x;
    if (e < E) atomicAdd(&cnt[dst[e]], 1);
}

__global__ void dis_kernel(const int* __restrict__ cnt, float* __restrict__ dis, int n) {
    int i = blockIdx.x * blockDim.x + threadIdx.x;
    if (i < n) dis[i] = rsqrtf(1.0f + (float)cnt[i]);   // +1 self-loop
}

__global__ void scan_partial_kernel(const int* __restrict__ cnt, int* __restrict__ partial, int n) {
    __shared__ int sh[256];
    int i = blockIdx.x * 256 + threadIdx.x;
    int v = (i < n) ? cnt[i] : 0;
    sh[threadIdx.x] = v;
    __syncthreads();
    for (int ofs = 128; ofs > 0; ofs >>= 1) {
        if (threadIdx.x < ofs) sh[threadIdx.x] += sh[threadIdx.x + ofs];
        __syncthreads();
    }
    if (threadIdx.x == 0) partial[blockIdx.x] = sh[0];
}

__global__ void scan_top_kernel(int* __restrict__ partial, int nb, int* __restrict__ row_ptr, int n) {
    if (blockIdx.x == 0 && threadIdx.x == 0) {
        int run = 0;
        for (int b = 0; b < nb; ++b) { int v = partial[b]; partial[b] = run; run += v; }
        row_ptr[n] = run;
    }
}

__global__ void scan_final_kernel(const int* __restrict__ cnt, const int* __restrict__ partial,
                                  int* __restrict__ row_ptr, int n) {
    __shared__ int sh[256];
    int i = blockIdx.x * 256 + threadIdx.x;
    int v = (i < n) ? cnt[i] : 0;
    sh[threadIdx.x] = v;
    __syncthreads();
    for (int ofs = 1; ofs < 256; ofs <<= 1) {
        int t = 0;
        if (threadIdx.x >= ofs) t = sh[threadIdx.x - ofs];
        __syncthreads();
        if (threadIdx.x >= ofs) sh[threadIdx.x] += t;
        __syncthreads();
    }
    if (i < n) row_ptr[i] = partial[blockIdx.x] + sh[threadIdx.x] - v;  // exclusive
}

__global__ void fill_kernel(const int* __restrict__ src, const int* __restrict__ dst,
                            const int* __restrict__ row_ptr, int* __restrict__ cursor,
                            int* __restrict__ csr_src, int E) {
    int e = blockIdx.x * blockDim.x + threadIdx.x;
    if (e >= E) return;
    int d = dst[e];
    int p = row_ptr[d] + atomicAdd(&cursor[d], 1);
    csr_src[p] = src[e];
}

// ---------------- GEMM 1: g1 = dis .* (X[n,256] @ W1[256,128]) ----------------

__global__ __launch_bounds__(256) void gemm1_kernel(
    const float* __restrict__ X, const float* __restrict__ W,
    const float* __restrict__ dis, float* __restrict__ G, int n) {
    constexpr int BM = 64, BN = 128, BK = 32, K = 256;
    __shared__ float xs[BM * BK];
    __shared__ float ws[BK * BN];
    int tid = threadIdx.x;
    int block_row = blockIdx.x * BM;
    int ty = tid >> 4;   // 0..15 -> 4 rows each
    int tx = tid & 15;   // 0..15 -> 8 cols each
    float acc[4][8];
    #pragma unroll
    for (int r = 0; r < 4; ++r)
        #pragma unroll
        for (int c = 0; c < 8; ++c) acc[r][c] = 0.f;

    for (int kb = 0; kb < K; kb += BK) {
        #pragma unroll
        for (int j = 0; j < 2; ++j) {      // 512 float4 of X-tile
            int idx = tid + j * 256;
            int row = idx >> 3, k4 = idx & 7;
            int grow = block_row + row;
            float4 v = make_float4(0.f, 0.f, 0.f, 0.f);
            if (grow < n) v = *(const float4*)&X[(size_t)grow * K + kb + k4 * 4];
            *(float4*)&xs[row * BK + k4 * 4] = v;
        }
        #pragma unroll
        for (int j = 0; j < 4; ++j) {      // 1024 float4 of W-tile
            int idx = tid + j * 256;
            int k = idx >> 5, c4 = idx & 31;
            float4 v = *(const float4*)&W[(kb + k) * BN + c4 * 4];
            *(float4*)&ws[k * BN + c4 * 4] = v;
        }
        __syncthreads();
        #pragma unroll
        for (int kk = 0; kk < BK; ++kk) {
            float a[4];
            #pragma unroll
            for (int r = 0; r < 4; ++r) a[r] = xs[(ty * 4 + r) * BK + kk];
            float b[8];
            *(float4*)&b[0] = *(const float4*)&ws[kk * BN + tx * 8];
            *(float4*)&b[4] = *(const float4*)&ws[kk * BN + tx * 8 + 4];
            #pragma unroll
            for (int r = 0; r < 4; ++r)
                #pragma unroll
                for (int c = 0; c < 8; ++c) acc[r][c] = fmaf(a[r], b[c], acc[r][c]);
        }
        __syncthreads();
    }
    #pragma unroll
    for (int r = 0; r < 4; ++r) {
        int grow = block_row + ty * 4 + r;
        if (grow < n) {
            float d = dis[grow];
            float o[8];
            #pragma unroll
            for (int c = 0; c < 8; ++c) o[c] = acc[r][c] * d;
            *(float4*)&G[(size_t)grow * BN + tx * 8]     = *(const float4*)&o[0];
            *(float4*)&G[(size_t)grow * BN + tx * 8 + 4] = *(const float4*)&o[4];
        }
    }
}

// ---------------- GEMM 2: g2 = dis .* (H[n,128] @ W2[128,64]) ----------------

__global__ __launch_bounds__(256) void gemm2_kernel(
    const float* __restrict__ H, const float* __restrict__ W,
    const float* __restrict__ dis, float* __restrict__ G, int n) {
    constexpr int BM = 64, BN = 64, BK = 32, K = 128;
    __shared__ float hs[BM * BK];
    __shared__ float ws[BK * BN];
    int tid = threadIdx.x;
    int block_row = blockIdx.x * BM;
    int ty = tid >> 4;   // 4 rows each
    int tx = tid & 15;   // 4 cols each
    float acc[4][4];
    #pragma unroll
    for (int r = 0; r < 4; ++r)
        #pragma unroll
        for (int c = 0; c < 4; ++c) acc[r][c] = 0.f;

    for (int kb = 0; kb < K; kb += BK) {
        #pragma unroll
        for (int j = 0; j < 2; ++j) {      // 512 float4 of H-tile
            int idx = tid + j * 256;
            int row = idx >> 3, k4 = idx & 7;
            int grow = block_row + row;
            float4 v = make_float4(0.f, 0.f, 0.f, 0.f);
            if (grow < n) v = *(const float4*)&H[(size_t)grow * K + kb + k4 * 4];
            *(float4*)&hs[row * BK + k4 * 4] = v;
        }
        #pragma unroll
        for (int j = 0; j < 2; ++j) {      // 512 float4 of W-tile
            int idx = tid + j * 256;
            int k = idx >> 4, c4 = idx & 15;
            float4 v = *(const float4*)&W[(kb + k) * BN + c4 * 4];
            *(float4*)&ws[k * BN + c4 * 4] = v;
        }
        __syncthreads();
        #pragma unroll
        for (int kk = 0; kk < BK; ++kk) {
            float a[4];
            #pragma unroll
            for (int r = 0; r < 4; ++r) a[r] = hs[(ty * 4 + r) * BK + kk];
            float b[4];
            *(float4*)&b[0] = *(const float4*)&ws[kk * BN + tx * 4];
            #pragma unroll
            for (int r = 0; r < 4; ++r)
                #pragma unroll
                for (int c = 0; c < 4; ++c) acc[r][c] = fmaf(a[r], b[c], acc[r][c]);
        }
        __syncthreads();
    }
    #pragma unroll
    for (int r = 0; r < 4; ++r) {
        int grow = block_row + ty * 4 + r;
        if (grow < n) {
            float d = dis[grow];
            float o[4];
            #pragma unroll
            for (int c = 0; c < 4; ++c) o[c] = acc[r][c] * d;
            *(float4*)&G[(size_t)grow * BN + tx * 4] = *(const float4*)&o[0];
        }
    }
}

// ---------------- Aggregation 1: h1 = relu(dis .* (self+gather) + b1) --------

__global__ __launch_bounds__(256) void agg1_kernel(
    const float* __restrict__ G, const int* __restrict__ row_ptr,
    const int* __restrict__ csr_src, const float* __restrict__ dis,
    const float* __restrict__ b1, float* __restrict__ H, int n) {
    int wave = (blockIdx.x * blockDim.x + threadIdx.x) >> 6;
    int lane = threadIdx.x & 63;
    if (wave >= n) return;
    const float2* Gv = (const float2*)G;
    float2 s = Gv[(size_t)wave * 64 + lane];          // self term g[i]
    int beg = row_ptr[wave], end = row_ptr[wave + 1];
    for (int e = beg; e < end; ++e) {
        int src = csr_src[e];
        float2 v = Gv[(size_t)src * 64 + lane];
        s.x += v.x; s.y += v.y;
    }
    float d = dis[wave];
    float2 bb = ((const float2*)b1)[lane];
    float o0 = fmaf(s.x, d, bb.x); o0 = o0 > 0.f ? o0 : 0.f;
    float o1 = fmaf(s.y, d, bb.y); o1 = o1 > 0.f ? o1 : 0.f;
    ((float2*)H)[(size_t)wave * 64 + lane] = make_float2(o0, o1);
}

// ---------------- Aggregation 2: out = dis .* (self+gather) + b2 -------------

__global__ __launch_bounds__(256) void agg2_kernel(
    const float* __restrict__ G, const int* __restrict__ row_ptr,
    const int* __restrict__ csr_src, const float* __restrict__ dis,
    const float* __restrict__ b2, float* __restrict__ out, int n) {
    int wave = (blockIdx.x * blockDim.x + threadIdx.x) >> 6;
    int lane = threadIdx.x & 63;
    if (wave >= n) return;
    float s = G[(size_t)wave * 64 + lane];
    int beg = row_ptr[wave], end = row_ptr[wave + 1];
    for (int e = beg; e < end; ++e) {
        int src = csr_src[e];
        s += G[(size_t)src * 64 + lane];
    }
    out[(size_t)wave * 64 + lane] = fmaf(s, dis[wave], b2[lane]);
}

// ---------------- launch ----------------

extern "C" void kernel_launch(void* const* d_in, const int* in_sizes, int n_in,
                              void* d_out, int out_size, void* d_ws, size_t ws_size,
                              hipStream_t stream) {
    const float* x  = (const float*)d_in[0];
    const int*   ei = (const int*)d_in[1];
    const float* W1 = (const float*)d_in[2];
    const float* b1 = (const float*)d_in[3];
    const float* W2 = (const float*)d_in[4];
    const float* b2 = (const float*)d_in[5];
    float* out = (float*)d_out;

    int n = in_sizes[0] / IN_CH;       // 100000
    int E = in_sizes[1] / 2;           // 1600000
    const int* srcv = ei;
    const int* dstv = ei + E;

    char* w = (char*)d_ws;
    float* g1 = (float*)w;  w += (size_t)n * HID * 4;        // 51.2 MB
    float* h1 = (float*)w;  w += (size_t)n * HID * 4;        // 51.2 MB
    float* g2 = g1;                                          // overlay (g1 dead by then)
    int*   cnt     = (int*)w;   w += (size_t)n * 4;
    float* dis     = (float*)w; w += (size_t)n * 4;
    int*   row_ptr = (int*)w;   w += (size_t)(n + 1) * 4;
    int*   cursor  = (int*)w;   w += (size_t)n * 4;
    int*   partial = (int*)w;   w += (size_t)1024 * 4;
    int*   csr     = (int*)w;   w += (size_t)E * 4;          // 6.4 MB

    int nb  = (n + 255) / 256;
    int ebk = (E + 255) / 256;

    hipMemsetAsync(cnt, 0, (size_t)n * 4, stream);
    hipMemsetAsync(cursor, 0, (size_t)n * 4, stream);

    hist_kernel<<<ebk, 256, 0, stream>>>(dstv, cnt, E);
    dis_kernel<<<nb, 256, 0, stream>>>(cnt, dis, n);
    scan_partial_kernel<<<nb, 256, 0, stream>>>(cnt, partial, n);
    scan_top_kernel<<<1, 64, 0, stream>>>(partial, nb, row_ptr, n);
    scan_final_kernel<<<nb, 256, 0, stream>>>(cnt, partial, row_ptr, n);
    fill_kernel<<<ebk, 256, 0, stream>>>(srcv, dstv, row_ptr, cursor, csr, E);

    gemm1_kernel<<<(n + 63) / 64, 256, 0, stream>>>(x, W1, dis, g1, n);
    agg1_kernel<<<(n + 3) / 4, 256, 0, stream>>>(g1, row_ptr, csr, dis, b1, h1, n);
    gemm2_kernel<<<(n + 63) / 64, 256, 0, stream>>>(h1, W2, dis, g2, n);
    agg2_kernel<<<(n + 3) / 4, 256, 0, stream>>>(g2, row_ptr, csr, dis, b2, out, n);
}

// Round 2
// 465.659 us; speedup vs baseline: 1.4700x; 1.4700x over previous
//
#include <hip/hip_runtime.h>

// ---------------------------------------------------------------------------
// GCN 2-layer forward on MI355X.
//  out = Ahat( relu( Ahat (X W1) + b1 ) W2 ) + b2,  Ahat = D^-1/2 (A+I) D^-1/2
// Factored: g = dis .* (X W);  s[i] = g[i] + sum_{e: dst=i} g[src[e]];
//           layer_out[i] = dis[i]*s[i] + b
// R2: agg kernels = shfl-broadcast indices + 4-deep gather pipelining;
//     parallel top-level scan; padded LDS A-tile stride (36) in GEMMs.
// ---------------------------------------------------------------------------

constexpr int IN_CH  = 256;
constexpr int HID    = 128;
constexpr int OUT_CH = 64;

// ---------------- CSR build ----------------

__global__ void hist_kernel(const int* __restrict__ dst, int* __restrict__ cnt, int E) {
    int e = blockIdx.x * blockDim.x + threadIdx.x;
    if (e < E) atomicAdd(&cnt[dst[e]], 1);
}

__global__ void dis_kernel(const int* __restrict__ cnt, float* __restrict__ dis, int n) {
    int i = blockIdx.x * blockDim.x + threadIdx.x;
    if (i < n) dis[i] = rsqrtf(1.0f + (float)cnt[i]);   // +1 self-loop
}

__global__ void scan_partial_kernel(const int* __restrict__ cnt, int* __restrict__ partial, int n) {
    __shared__ int sh[256];
    int i = blockIdx.x * 256 + threadIdx.x;
    int v = (i < n) ? cnt[i] : 0;
    sh[threadIdx.x] = v;
    __syncthreads();
    for (int ofs = 128; ofs > 0; ofs >>= 1) {
        if (threadIdx.x < ofs) sh[threadIdx.x] += sh[threadIdx.x + ofs];
        __syncthreads();
    }
    if (threadIdx.x == 0) partial[blockIdx.x] = sh[0];
}

// Parallel exclusive scan over up to 1024 block partials (one 1024-thread block).
__global__ __launch_bounds__(1024) void scan_top_kernel(
    int* __restrict__ partial, int nb, int* __restrict__ row_ptr, int n) {
    __shared__ int sh[1024];
    int t = threadIdx.x;
    int v = (t < nb) ? partial[t] : 0;
    sh[t] = v;
    __syncthreads();
    for (int ofs = 1; ofs < 1024; ofs <<= 1) {
        int tv = (t >= ofs) ? sh[t - ofs] : 0;
        __syncthreads();
        sh[t] += tv;
        __syncthreads();
    }
    if (t < nb) partial[t] = sh[t] - v;          // exclusive
    if (t == 1023) row_ptr[n] = sh[1023];        // grand total
}

__global__ void scan_final_kernel(const int* __restrict__ cnt, const int* __restrict__ partial,
                                  int* __restrict__ row_ptr, int n) {
    __shared__ int sh[256];
    int i = blockIdx.x * 256 + threadIdx.x;
    int v = (i < n) ? cnt[i] : 0;
    sh[threadIdx.x] = v;
    __syncthreads();
    for (int ofs = 1; ofs < 256; ofs <<= 1) {
        int t = 0;
        if (threadIdx.x >= ofs) t = sh[threadIdx.x - ofs];
        __syncthreads();
        if (threadIdx.x >= ofs) sh[threadIdx.x] += t;
        __syncthreads();
    }
    if (i < n) row_ptr[i] = partial[blockIdx.x] + sh[threadIdx.x] - v;  // exclusive
}

__global__ void fill_kernel(const int* __restrict__ src, const int* __restrict__ dst,
                            const int* __restrict__ row_ptr, int* __restrict__ cursor,
                            int* __restrict__ csr_src, int E) {
    int e = blockIdx.x * blockDim.x + threadIdx.x;
    if (e >= E) return;
    int d = dst[e];
    int p = row_ptr[d] + atomicAdd(&cursor[d], 1);
    csr_src[p] = src[e];
}

// ---------------- GEMM 1: g1 = dis .* (X[n,256] @ W1[256,128]) ----------------

__global__ __launch_bounds__(256) void gemm1_kernel(
    const float* __restrict__ X, const float* __restrict__ W,
    const float* __restrict__ dis, float* __restrict__ G, int n) {
    constexpr int BM = 64, BN = 128, BK = 32, K = 256;
    constexpr int XP = 36;                 // padded A-tile stride: bank-conflict-free, 16B aligned
    __shared__ float xs[BM * XP];
    __shared__ float ws[BK * BN];
    int tid = threadIdx.x;
    int block_row = blockIdx.x * BM;
    int ty = tid >> 4;   // 0..15 -> 4 rows each
    int tx = tid & 15;   // 0..15 -> 8 cols each
    float acc[4][8];
    #pragma unroll
    for (int r = 0; r < 4; ++r)
        #pragma unroll
        for (int c = 0; c < 8; ++c) acc[r][c] = 0.f;

    for (int kb = 0; kb < K; kb += BK) {
        #pragma unroll
        for (int j = 0; j < 2; ++j) {      // 512 float4 of X-tile
            int idx = tid + j * 256;
            int row = idx >> 3, k4 = idx & 7;
            int grow = block_row + row;
            float4 v = make_float4(0.f, 0.f, 0.f, 0.f);
            if (grow < n) v = *(const float4*)&X[(size_t)grow * K + kb + k4 * 4];
            *(float4*)&xs[row * XP + k4 * 4] = v;
        }
        #pragma unroll
        for (int j = 0; j < 4; ++j) {      // 1024 float4 of W-tile
            int idx = tid + j * 256;
            int k = idx >> 5, c4 = idx & 31;
            float4 v = *(const float4*)&W[(kb + k) * BN + c4 * 4];
            *(float4*)&ws[k * BN + c4 * 4] = v;
        }
        __syncthreads();
        #pragma unroll
        for (int kk = 0; kk < BK; ++kk) {
            float a[4];
            #pragma unroll
            for (int r = 0; r < 4; ++r) a[r] = xs[(ty * 4 + r) * XP + kk];
            float b[8];
            *(float4*)&b[0] = *(const float4*)&ws[kk * BN + tx * 8];
            *(float4*)&b[4] = *(const float4*)&ws[kk * BN + tx * 8 + 4];
            #pragma unroll
            for (int r = 0; r < 4; ++r)
                #pragma unroll
                for (int c = 0; c < 8; ++c) acc[r][c] = fmaf(a[r], b[c], acc[r][c]);
        }
        __syncthreads();
    }
    #pragma unroll
    for (int r = 0; r < 4; ++r) {
        int grow = block_row + ty * 4 + r;
        if (grow < n) {
            float d = dis[grow];
            float o[8];
            #pragma unroll
            for (int c = 0; c < 8; ++c) o[c] = acc[r][c] * d;
            *(float4*)&G[(size_t)grow * BN + tx * 8]     = *(const float4*)&o[0];
            *(float4*)&G[(size_t)grow * BN + tx * 8 + 4] = *(const float4*)&o[4];
        }
    }
}

// ---------------- GEMM 2: g2 = dis .* (H[n,128] @ W2[128,64]) ----------------

__global__ __launch_bounds__(256) void gemm2_kernel(
    const float* __restrict__ H, const float* __restrict__ W,
    const float* __restrict__ dis, float* __restrict__ G, int n) {
    constexpr int BM = 64, BN = 64, BK = 32, K = 128;
    constexpr int HP = 36;
    __shared__ float hs[BM * HP];
    __shared__ float ws[BK * BN];
    int tid = threadIdx.x;
    int block_row = blockIdx.x * BM;
    int ty = tid >> 4;   // 4 rows each
    int tx = tid & 15;   // 4 cols each
    float acc[4][4];
    #pragma unroll
    for (int r = 0; r < 4; ++r)
        #pragma unroll
        for (int c = 0; c < 4; ++c) acc[r][c] = 0.f;

    for (int kb = 0; kb < K; kb += BK) {
        #pragma unroll
        for (int j = 0; j < 2; ++j) {      // 512 float4 of H-tile
            int idx = tid + j * 256;
            int row = idx >> 3, k4 = idx & 7;
            int grow = block_row + row;
            float4 v = make_float4(0.f, 0.f, 0.f, 0.f);
            if (grow < n) v = *(const float4*)&H[(size_t)grow * K + kb + k4 * 4];
            *(float4*)&hs[row * HP + k4 * 4] = v;
        }
        #pragma unroll
        for (int j = 0; j < 2; ++j) {      // 512 float4 of W-tile
            int idx = tid + j * 256;
            int k = idx >> 4, c4 = idx & 15;
            float4 v = *(const float4*)&W[(kb + k) * BN + c4 * 4];
            *(float4*)&ws[k * BN + c4 * 4] = v;
        }
        __syncthreads();
        #pragma unroll
        for (int kk = 0; kk < BK; ++kk) {
            float a[4];
            #pragma unroll
            for (int r = 0; r < 4; ++r) a[r] = hs[(ty * 4 + r) * HP + kk];
            float b[4];
            *(float4*)&b[0] = *(const float4*)&ws[kk * BN + tx * 4];
            #pragma unroll
            for (int r = 0; r < 4; ++r)
                #pragma unroll
                for (int c = 0; c < 4; ++c) acc[r][c] = fmaf(a[r], b[c], acc[r][c]);
        }
        __syncthreads();
    }
    #pragma unroll
    for (int r = 0; r < 4; ++r) {
        int grow = block_row + ty * 4 + r;
        if (grow < n) {
            float d = dis[grow];
            float o[4];
            #pragma unroll
            for (int c = 0; c < 4; ++c) o[c] = acc[r][c] * d;
            *(float4*)&G[(size_t)grow * BN + tx * 4] = *(const float4*)&o[0];
        }
    }
}

// ---------------- Aggregation 1: h1 = relu(dis .* (self+gather) + b1) --------
// One wave per node, float2 (2 ch) per lane. Indices: one coalesced load per
// 64 edges + __shfl broadcast. Gathers pipelined 4-deep (4 accumulators).

__global__ __launch_bounds__(256) void agg1_kernel(
    const float* __restrict__ G, const int* __restrict__ row_ptr,
    const int* __restrict__ csr_src, const float* __restrict__ dis,
    const float* __restrict__ b1, float* __restrict__ H, int n) {
    int wid = (blockIdx.x * blockDim.x + threadIdx.x) >> 6;
    int lane = threadIdx.x & 63;
    if (wid >= n) return;
    const float2* Gv = (const float2*)G;
    float2 s0 = Gv[(size_t)wid * 64 + lane];          // self term g[i]
    float2 s1 = make_float2(0.f, 0.f);
    float2 s2 = make_float2(0.f, 0.f);
    float2 s3 = make_float2(0.f, 0.f);
    int beg = row_ptr[wid], end = row_ptr[wid + 1];
    for (int base = beg; base < end; base += 64) {
        int m = end - base; if (m > 64) m = 64;
        int idx = csr_src[base + (lane < m ? lane : m - 1)];
        int j = 0;
        for (; j + 4 <= m; j += 4) {
            int ia = __shfl(idx, j);
            int ib = __shfl(idx, j + 1);
            int ic = __shfl(idx, j + 2);
            int id = __shfl(idx, j + 3);
            float2 va = Gv[(size_t)ia * 64 + lane];
            float2 vb = Gv[(size_t)ib * 64 + lane];
            float2 vc = Gv[(size_t)ic * 64 + lane];
            float2 vd = Gv[(size_t)id * 64 + lane];
            s0.x += va.x; s0.y += va.y;
            s1.x += vb.x; s1.y += vb.y;
            s2.x += vc.x; s2.y += vc.y;
            s3.x += vd.x; s3.y += vd.y;
        }
        for (; j < m; ++j) {
            int ia = __shfl(idx, j);
            float2 va = Gv[(size_t)ia * 64 + lane];
            s0.x += va.x; s0.y += va.y;
        }
    }
    s0.x += s1.x + s2.x + s3.x;
    s0.y += s1.y + s2.y + s3.y;
    float d = dis[wid];
    float2 bb = ((const float2*)b1)[lane];
    float o0 = fmaf(s0.x, d, bb.x); o0 = o0 > 0.f ? o0 : 0.f;
    float o1 = fmaf(s0.y, d, bb.y); o1 = o1 > 0.f ? o1 : 0.f;
    ((float2*)H)[(size_t)wid * 64 + lane] = make_float2(o0, o1);
}

// ---------------- Aggregation 2: out = dis .* (self+gather) + b2 -------------

__global__ __launch_bounds__(256) void agg2_kernel(
    const float* __restrict__ G, const int* __restrict__ row_ptr,
    const int* __restrict__ csr_src, const float* __restrict__ dis,
    const float* __restrict__ b2, float* __restrict__ out, int n) {
    int wid = (blockIdx.x * blockDim.x + threadIdx.x) >> 6;
    int lane = threadIdx.x & 63;
    if (wid >= n) return;
    float s0 = G[(size_t)wid * 64 + lane];
    float s1 = 0.f, s2 = 0.f, s3 = 0.f;
    int beg = row_ptr[wid], end = row_ptr[wid + 1];
    for (int base = beg; base < end; base += 64) {
        int m = end - base; if (m > 64) m = 64;
        int idx = csr_src[base + (lane < m ? lane : m - 1)];
        int j = 0;
        for (; j + 4 <= m; j += 4) {
            int ia = __shfl(idx, j);
            int ib = __shfl(idx, j + 1);
            int ic = __shfl(idx, j + 2);
            int id = __shfl(idx, j + 3);
            s0 += G[(size_t)ia * 64 + lane];
            s1 += G[(size_t)ib * 64 + lane];
            s2 += G[(size_t)ic * 64 + lane];
            s3 += G[(size_t)id * 64 + lane];
        }
        for (; j < m; ++j) {
            int ia = __shfl(idx, j);
            s0 += G[(size_t)ia * 64 + lane];
        }
    }
    s0 += s1 + s2 + s3;
    out[(size_t)wid * 64 + lane] = fmaf(s0, dis[wid], b2[lane]);
}

// ---------------- launch ----------------

extern "C" void kernel_launch(void* const* d_in, const int* in_sizes, int n_in,
                              void* d_out, int out_size, void* d_ws, size_t ws_size,
                              hipStream_t stream) {
    const float* x  = (const float*)d_in[0];
    const int*   ei = (const int*)d_in[1];
    const float* W1 = (const float*)d_in[2];
    const float* b1 = (const float*)d_in[3];
    const float* W2 = (const float*)d_in[4];
    const float* b2 = (const float*)d_in[5];
    float* out = (float*)d_out;

    int n = in_sizes[0] / IN_CH;       // 100000
    int E = in_sizes[1] / 2;           // 1600000
    const int* srcv = ei;
    const int* dstv = ei + E;

    char* w = (char*)d_ws;
    float* g1 = (float*)w;  w += (size_t)n * HID * 4;        // 51.2 MB
    float* h1 = (float*)w;  w += (size_t)n * HID * 4;        // 51.2 MB
    float* g2 = g1;                                          // overlay (g1 dead by then)
    int*   cnt     = (int*)w;   w += (size_t)n * 4;
    float* dis     = (float*)w; w += (size_t)n * 4;
    int*   row_ptr = (int*)w;   w += (size_t)(n + 1) * 4;
    int*   cursor  = (int*)w;   w += (size_t)n * 4;
    int*   partial = (int*)w;   w += (size_t)1024 * 4;
    int*   csr     = (int*)w;   w += (size_t)E * 4;          // 6.4 MB

    int nb  = (n + 255) / 256;
    int ebk = (E + 255) / 256;

    hipMemsetAsync(cnt, 0, (size_t)n * 4, stream);
    hipMemsetAsync(cursor, 0, (size_t)n * 4, stream);

    hist_kernel<<<ebk, 256, 0, stream>>>(dstv, cnt, E);
    dis_kernel<<<nb, 256, 0, stream>>>(cnt, dis, n);
    scan_partial_kernel<<<nb, 256, 0, stream>>>(cnt, partial, n);
    scan_top_kernel<<<1, 1024, 0, stream>>>(partial, nb, row_ptr, n);
    scan_final_kernel<<<nb, 256, 0, stream>>>(cnt, partial, row_ptr, n);
    fill_kernel<<<ebk, 256, 0, stream>>>(srcv, dstv, row_ptr, cursor, csr, E);

    gemm1_kernel<<<(n + 63) / 64, 256, 0, stream>>>(x, W1, dis, g1, n);
    agg1_kernel<<<(n + 3) / 4, 256, 0, stream>>>(g1, row_ptr, csr, dis, b1, h1, n);
    gemm2_kernel<<<(n + 63) / 64, 256, 0, stream>>>(h1, W2, dis, g2, n);
    agg2_kernel<<<(n + 3) / 4, 256, 0, stream>>>(g2, row_ptr, csr, dis, b2, out, n);
}

// Round 3
// 361.006 us; speedup vs baseline: 1.8962x; 1.2899x over previous
//
#include <hip/hip_runtime.h>

// ---------------------------------------------------------------------------
// GCN 2-layer forward on MI355X.
//  out = Ahat( relu( Ahat (X W1) + b1 ) W2 ) + b2,  Ahat = D^-1/2 (A+I) D^-1/2
// Factored: g = dis .* (X W);  s[i] = g[i] + sum_{e: dst=i} g[src[e]];
//           layer_out[i] = dis[i]*s[i] + b
// R3: CSR fill without atomics (rank captured in hist); bf16 G-buffers so the
//     irregular gathers move half the bytes (and cache-fit better);
//     dis fused into scan_final.
// ---------------------------------------------------------------------------

constexpr int IN_CH  = 256;
constexpr int HID    = 128;
constexpr int OUT_CH = 64;

// ---- bf16 helpers (manual: OCP bf16 = top 16 bits of f32, RNE) ----

__device__ inline unsigned pack_bf16(float a, float b) {
    unsigned ua = __float_as_uint(a); ua += 0x7fffu + ((ua >> 16) & 1u);
    unsigned ub = __float_as_uint(b); ub += 0x7fffu + ((ub >> 16) & 1u);
    return (ua >> 16) | (ub & 0xffff0000u);
}
__device__ inline float2 unpack_bf16(unsigned v) {
    return make_float2(__uint_as_float(v << 16), __uint_as_float(v & 0xffff0000u));
}
__device__ inline float bf16_to_f32(unsigned short h) {
    return __uint_as_float(((unsigned)h) << 16);
}

// ---------------- CSR build ----------------

// rank[e] = this edge's arrival index among edges sharing dst -> unique slot.
__global__ void hist_kernel(const int* __restrict__ dst, int* __restrict__ cnt,
                            int* __restrict__ rank, int E) {
    int e = blockIdx.x * blockDim.x + threadIdx.x;
    if (e < E) rank[e] = atomicAdd(&cnt[dst[e]], 1);
}

__global__ void scan_partial_kernel(const int* __restrict__ cnt, int* __restrict__ partial, int n) {
    __shared__ int sh[256];
    int i = blockIdx.x * 256 + threadIdx.x;
    int v = (i < n) ? cnt[i] : 0;
    sh[threadIdx.x] = v;
    __syncthreads();
    for (int ofs = 128; ofs > 0; ofs >>= 1) {
        if (threadIdx.x < ofs) sh[threadIdx.x] += sh[threadIdx.x + ofs];
        __syncthreads();
    }
    if (threadIdx.x == 0) partial[blockIdx.x] = sh[0];
}

// Parallel exclusive scan over up to 1024 block partials (one 1024-thread block).
__global__ __launch_bounds__(1024) void scan_top_kernel(
    int* __restrict__ partial, int nb, int* __restrict__ row_ptr, int n) {
    __shared__ int sh[1024];
    int t = threadIdx.x;
    int v = (t < nb) ? partial[t] : 0;
    sh[t] = v;
    __syncthreads();
    for (int ofs = 1; ofs < 1024; ofs <<= 1) {
        int tv = (t >= ofs) ? sh[t - ofs] : 0;
        __syncthreads();
        sh[t] += tv;
        __syncthreads();
    }
    if (t < nb) partial[t] = sh[t] - v;          // exclusive
    if (t == 1023) row_ptr[n] = sh[1023];        // grand total
}

// Also computes dis[i] = rsqrt(deg_i + 1) (self-loop).
__global__ void scan_final_kernel(const int* __restrict__ cnt, const int* __restrict__ partial,
                                  int* __restrict__ row_ptr, float* __restrict__ dis, int n) {
    __shared__ int sh[256];
    int i = blockIdx.x * 256 + threadIdx.x;
    int v = (i < n) ? cnt[i] : 0;
    sh[threadIdx.x] = v;
    __syncthreads();
    for (int ofs = 1; ofs < 256; ofs <<= 1) {
        int t = 0;
        if (threadIdx.x >= ofs) t = sh[threadIdx.x - ofs];
        __syncthreads();
        if (threadIdx.x >= ofs) sh[threadIdx.x] += t;
        __syncthreads();
    }
    if (i < n) {
        row_ptr[i] = partial[blockIdx.x] + sh[threadIdx.x] - v;  // exclusive
        dis[i] = rsqrtf(1.0f + (float)v);
    }
}

// No atomics: slot = row_ptr[dst] + rank.
__global__ void fill_kernel(const int* __restrict__ src, const int* __restrict__ dst,
                            const int* __restrict__ row_ptr, const int* __restrict__ rank,
                            int* __restrict__ csr_src, int E) {
    int e = blockIdx.x * blockDim.x + threadIdx.x;
    if (e >= E) return;
    csr_src[row_ptr[dst[e]] + rank[e]] = src[e];
}

// ---------------- GEMM 1: g1 = bf16( dis .* (X[n,256] @ W1[256,128]) ) -------

__global__ __launch_bounds__(256) void gemm1_kernel(
    const float* __restrict__ X, const float* __restrict__ W,
    const float* __restrict__ dis, unsigned* __restrict__ G, int n) {
    constexpr int BM = 64, BN = 128, BK = 32, K = 256;
    constexpr int XP = 36;                 // padded A-tile stride
    __shared__ float xs[BM * XP];
    __shared__ float ws[BK * BN];
    int tid = threadIdx.x;
    int block_row = blockIdx.x * BM;
    int ty = tid >> 4;   // 0..15 -> 4 rows each
    int tx = tid & 15;   // 0..15 -> 8 cols each
    float acc[4][8];
    #pragma unroll
    for (int r = 0; r < 4; ++r)
        #pragma unroll
        for (int c = 0; c < 8; ++c) acc[r][c] = 0.f;

    for (int kb = 0; kb < K; kb += BK) {
        #pragma unroll
        for (int j = 0; j < 2; ++j) {      // 512 float4 of X-tile
            int idx = tid + j * 256;
            int row = idx >> 3, k4 = idx & 7;
            int grow = block_row + row;
            float4 v = make_float4(0.f, 0.f, 0.f, 0.f);
            if (grow < n) v = *(const float4*)&X[(size_t)grow * K + kb + k4 * 4];
            *(float4*)&xs[row * XP + k4 * 4] = v;
        }
        #pragma unroll
        for (int j = 0; j < 4; ++j) {      // 1024 float4 of W-tile
            int idx = tid + j * 256;
            int k = idx >> 5, c4 = idx & 31;
            float4 v = *(const float4*)&W[(kb + k) * BN + c4 * 4];
            *(float4*)&ws[k * BN + c4 * 4] = v;
        }
        __syncthreads();
        #pragma unroll
        for (int kk = 0; kk < BK; ++kk) {
            float a[4];
            #pragma unroll
            for (int r = 0; r < 4; ++r) a[r] = xs[(ty * 4 + r) * XP + kk];
            float b[8];
            *(float4*)&b[0] = *(const float4*)&ws[kk * BN + tx * 8];
            *(float4*)&b[4] = *(const float4*)&ws[kk * BN + tx * 8 + 4];
            #pragma unroll
            for (int r = 0; r < 4; ++r)
                #pragma unroll
                for (int c = 0; c < 8; ++c) acc[r][c] = fmaf(a[r], b[c], acc[r][c]);
        }
        __syncthreads();
    }
    #pragma unroll
    for (int r = 0; r < 4; ++r) {
        int grow = block_row + ty * 4 + r;
        if (grow < n) {
            float d = dis[grow];
            uint4 o;
            o.x = pack_bf16(acc[r][0] * d, acc[r][1] * d);
            o.y = pack_bf16(acc[r][2] * d, acc[r][3] * d);
            o.z = pack_bf16(acc[r][4] * d, acc[r][5] * d);
            o.w = pack_bf16(acc[r][6] * d, acc[r][7] * d);
            *(uint4*)&G[(size_t)grow * 64 + tx * 4] = o;   // 64 uints per row (128 bf16)
        }
    }
}

// ---------------- GEMM 2: g2 = bf16( dis .* (H[n,128] @ W2[128,64]) ) --------

__global__ __launch_bounds__(256) void gemm2_kernel(
    const float* __restrict__ H, const float* __restrict__ W,
    const float* __restrict__ dis, unsigned* __restrict__ G, int n) {
    constexpr int BM = 64, BN = 64, BK = 32, K = 128;
    constexpr int HP = 36;
    __shared__ float hs[BM * HP];
    __shared__ float ws[BK * BN];
    int tid = threadIdx.x;
    int block_row = blockIdx.x * BM;
    int ty = tid >> 4;   // 4 rows each
    int tx = tid & 15;   // 4 cols each
    float acc[4][4];
    #pragma unroll
    for (int r = 0; r < 4; ++r)
        #pragma unroll
        for (int c = 0; c < 4; ++c) acc[r][c] = 0.f;

    for (int kb = 0; kb < K; kb += BK) {
        #pragma unroll
        for (int j = 0; j < 2; ++j) {      // 512 float4 of H-tile
            int idx = tid + j * 256;
            int row = idx >> 3, k4 = idx & 7;
            int grow = block_row + row;
            float4 v = make_float4(0.f, 0.f, 0.f, 0.f);
            if (grow < n) v = *(const float4*)&H[(size_t)grow * K + kb + k4 * 4];
            *(float4*)&hs[row * HP + k4 * 4] = v;
        }
        #pragma unroll
        for (int j = 0; j < 2; ++j) {      // 512 float4 of W-tile
            int idx = tid + j * 256;
            int k = idx >> 4, c4 = idx & 15;
            float4 v = *(const float4*)&W[(kb + k) * BN + c4 * 4];
            *(float4*)&ws[k * BN + c4 * 4] = v;
        }
        __syncthreads();
        #pragma unroll
        for (int kk = 0; kk < BK; ++kk) {
            float a[4];
            #pragma unroll
            for (int r = 0; r < 4; ++r) a[r] = hs[(ty * 4 + r) * HP + kk];
            float b[4];
            *(float4*)&b[0] = *(const float4*)&ws[kk * BN + tx * 4];
            #pragma unroll
            for (int r = 0; r < 4; ++r)
                #pragma unroll
                for (int c = 0; c < 4; ++c) acc[r][c] = fmaf(a[r], b[c], acc[r][c]);
        }
        __syncthreads();
    }
    #pragma unroll
    for (int r = 0; r < 4; ++r) {
        int grow = block_row + ty * 4 + r;
        if (grow < n) {
            float d = dis[grow];
            uint2 o;
            o.x = pack_bf16(acc[r][0] * d, acc[r][1] * d);
            o.y = pack_bf16(acc[r][2] * d, acc[r][3] * d);
            *(uint2*)&G[(size_t)grow * 32 + tx * 2] = o;   // 32 uints per row (64 bf16)
        }
    }
}

// ---------------- Aggregation 1: h1 = relu(dis .* (self+gather) + b1) --------
// One wave per node. bf16 G rows: 128ch = 64 uints; lane owns channels
// (2*lane, 2*lane+1). Indices shfl-broadcast; gathers pipelined 4-deep.

__global__ __launch_bounds__(256) void agg1_kernel(
    const unsigned* __restrict__ G, const int* __restrict__ row_ptr,
    const int* __restrict__ csr_src, const float* __restrict__ dis,
    const float* __restrict__ b1, float* __restrict__ H, int n) {
    int wid = (blockIdx.x * blockDim.x + threadIdx.x) >> 6;
    int lane = threadIdx.x & 63;
    if (wid >= n) return;
    float2 s0 = unpack_bf16(G[(size_t)wid * 64 + lane]);   // self term
    float2 s1 = make_float2(0.f, 0.f);
    float2 s2 = make_float2(0.f, 0.f);
    float2 s3 = make_float2(0.f, 0.f);
    int beg = row_ptr[wid], end = row_ptr[wid + 1];
    for (int base = beg; base < end; base += 64) {
        int m = end - base; if (m > 64) m = 64;
        int idx = csr_src[base + (lane < m ? lane : m - 1)];
        int j = 0;
        for (; j + 4 <= m; j += 4) {
            int ia = __shfl(idx, j);
            int ib = __shfl(idx, j + 1);
            int ic = __shfl(idx, j + 2);
            int id = __shfl(idx, j + 3);
            unsigned ua = G[(size_t)ia * 64 + lane];
            unsigned ub = G[(size_t)ib * 64 + lane];
            unsigned uc = G[(size_t)ic * 64 + lane];
            unsigned ud = G[(size_t)id * 64 + lane];
            float2 va = unpack_bf16(ua); s0.x += va.x; s0.y += va.y;
            float2 vb = unpack_bf16(ub); s1.x += vb.x; s1.y += vb.y;
            float2 vc = unpack_bf16(uc); s2.x += vc.x; s2.y += vc.y;
            float2 vd = unpack_bf16(ud); s3.x += vd.x; s3.y += vd.y;
        }
        for (; j < m; ++j) {
            int ia = __shfl(idx, j);
            float2 va = unpack_bf16(G[(size_t)ia * 64 + lane]);
            s0.x += va.x; s0.y += va.y;
        }
    }
    s0.x += s1.x + s2.x + s3.x;
    s0.y += s1.y + s2.y + s3.y;
    float d = dis[wid];
    float2 bb = ((const float2*)b1)[lane];
    float o0 = fmaf(s0.x, d, bb.x); o0 = o0 > 0.f ? o0 : 0.f;
    float o1 = fmaf(s0.y, d, bb.y); o1 = o1 > 0.f ? o1 : 0.f;
    ((float2*)H)[(size_t)wid * 64 + lane] = make_float2(o0, o1);
}

// ---------------- Aggregation 2: out = dis .* (self+gather) + b2 -------------
// bf16 G rows: 64ch = 64 ushorts; lane owns channel `lane`.

__global__ __launch_bounds__(256) void agg2_kernel(
    const unsigned short* __restrict__ G, const int* __restrict__ row_ptr,
    const int* __restrict__ csr_src, const float* __restrict__ dis,
    const float* __restrict__ b2, float* __restrict__ out, int n) {
    int wid = (blockIdx.x * blockDim.x + threadIdx.x) >> 6;
    int lane = threadIdx.x & 63;
    if (wid >= n) return;
    float s0 = bf16_to_f32(G[(size_t)wid * 64 + lane]);
    float s1 = 0.f, s2 = 0.f, s3 = 0.f;
    int beg = row_ptr[wid], end = row_ptr[wid + 1];
    for (int base = beg; base < end; base += 64) {
        int m = end - base; if (m > 64) m = 64;
        int idx = csr_src[base + (lane < m ? lane : m - 1)];
        int j = 0;
        for (; j + 4 <= m; j += 4) {
            int ia = __shfl(idx, j);
            int ib = __shfl(idx, j + 1);
            int ic = __shfl(idx, j + 2);
            int id = __shfl(idx, j + 3);
            s0 += bf16_to_f32(G[(size_t)ia * 64 + lane]);
            s1 += bf16_to_f32(G[(size_t)ib * 64 + lane]);
            s2 += bf16_to_f32(G[(size_t)ic * 64 + lane]);
            s3 += bf16_to_f32(G[(size_t)id * 64 + lane]);
        }
        for (; j < m; ++j) {
            int ia = __shfl(idx, j);
            s0 += bf16_to_f32(G[(size_t)ia * 64 + lane]);
        }
    }
    s0 += s1 + s2 + s3;
    out[(size_t)wid * 64 + lane] = fmaf(s0, dis[wid], b2[lane]);
}

// ---------------- launch ----------------

extern "C" void kernel_launch(void* const* d_in, const int* in_sizes, int n_in,
                              void* d_out, int out_size, void* d_ws, size_t ws_size,
                              hipStream_t stream) {
    const float* x  = (const float*)d_in[0];
    const int*   ei = (const int*)d_in[1];
    const float* W1 = (const float*)d_in[2];
    const float* b1 = (const float*)d_in[3];
    const float* W2 = (const float*)d_in[4];
    const float* b2 = (const float*)d_in[5];
    float* out = (float*)d_out;

    int n = in_sizes[0] / IN_CH;       // 100000
    int E = in_sizes[1] / 2;           // 1600000
    const int* srcv = ei;
    const int* dstv = ei + E;

    char* w = (char*)d_ws;
    unsigned* g1 = (unsigned*)w;  w += (size_t)n * HID * 2;      // 25.6 MB (bf16)
    float*    h1 = (float*)w;     w += (size_t)n * HID * 4;      // 51.2 MB (f32)
    unsigned* g2 = g1;                                           // overlay (g1 dead by then)
    int*   cnt     = (int*)w;   w += (size_t)n * 4;
    float* dis     = (float*)w; w += (size_t)n * 4;
    int*   row_ptr = (int*)w;   w += (size_t)(n + 1) * 4;
    int*   partial = (int*)w;   w += (size_t)1024 * 4;
    int*   rank    = (int*)w;   w += (size_t)E * 4;              // 6.4 MB
    int*   csr     = (int*)w;   w += (size_t)E * 4;              // 6.4 MB

    int nb  = (n + 255) / 256;
    int ebk = (E + 255) / 256;

    hipMemsetAsync(cnt, 0, (size_t)n * 4, stream);

    hist_kernel<<<ebk, 256, 0, stream>>>(dstv, cnt, rank, E);
    scan_partial_kernel<<<nb, 256, 0, stream>>>(cnt, partial, n);
    scan_top_kernel<<<1, 1024, 0, stream>>>(partial, nb, row_ptr, n);
    scan_final_kernel<<<nb, 256, 0, stream>>>(cnt, partial, row_ptr, dis, n);
    fill_kernel<<<ebk, 256, 0, stream>>>(srcv, dstv, row_ptr, rank, csr, E);

    gemm1_kernel<<<(n + 63) / 64, 256, 0, stream>>>(x, W1, dis, g1, n);
    agg1_kernel<<<(n + 3) / 4, 256, 0, stream>>>(g1, row_ptr, csr, dis, b1, h1, n);
    gemm2_kernel<<<(n + 63) / 64, 256, 0, stream>>>(h1, W2, dis, g2, n);
    agg2_kernel<<<(n + 3) / 4, 256, 0, stream>>>((const unsigned short*)g2, row_ptr, csr, dis, b2, out, n);
}

// Round 4
// 326.308 us; speedup vs baseline: 2.0978x; 1.1063x over previous
//
#include <hip/hip_runtime.h>

// ---------------------------------------------------------------------------
// GCN 2-layer forward on MI355X.
//  out = Ahat( relu( Ahat (X W1) + b1 ) W2 ) + b2,  Ahat = D^-1/2 (A+I) D^-1/2
// Factored: g = dis .* (X W);  s[i] = g[i] + sum_{e: dst=i} g[src[e]];
//           layer_out[i] = dis[i]*s[i] + b
// R4: GEMMs -> bf16 MFMA (16x16x32), zero LDS: A-frags loaded straight from
//     global (f32->bf16 in-register for layer 1), B-frags from pre-transposed
//     bf16 W^T (L1/L2-resident). agg1 now emits bf16 h1 (halves gemm2 reads).
// ---------------------------------------------------------------------------

constexpr int IN_CH  = 256;
constexpr int HID    = 128;
constexpr int OUT_CH = 64;

typedef __attribute__((ext_vector_type(8))) short short8;
typedef __attribute__((ext_vector_type(4))) float f32x4;

union F8 {                       // one MFMA A/B fragment: 8 bf16
    short8 v;
    unsigned short u[8];
    uint4  q;
};

// ---- bf16 helpers (RNE) ----
__device__ inline unsigned short f2b(float f) {
    unsigned u = __float_as_uint(f);
    u += 0x7fffu + ((u >> 16) & 1u);
    return (unsigned short)(u >> 16);
}
__device__ inline unsigned pack_bf16(float a, float b) {
    unsigned ua = __float_as_uint(a); ua += 0x7fffu + ((ua >> 16) & 1u);
    unsigned ub = __float_as_uint(b); ub += 0x7fffu + ((ub >> 16) & 1u);
    return (ua >> 16) | (ub & 0xffff0000u);
}
__device__ inline float2 unpack_bf16(unsigned v) {
    return make_float2(__uint_as_float(v << 16), __uint_as_float(v & 0xffff0000u));
}
__device__ inline float bf16_to_f32(unsigned short h) {
    return __uint_as_float(((unsigned)h) << 16);
}

// ---------------- CSR build ----------------

__global__ void hist_kernel(const int* __restrict__ dst, int* __restrict__ cnt,
                            int* __restrict__ rank, int E) {
    int e = blockIdx.x * blockDim.x + threadIdx.x;
    if (e < E) rank[e] = atomicAdd(&cnt[dst[e]], 1);
}

__global__ void scan_partial_kernel(const int* __restrict__ cnt, int* __restrict__ partial, int n) {
    __shared__ int sh[256];
    int i = blockIdx.x * 256 + threadIdx.x;
    int v = (i < n) ? cnt[i] : 0;
    sh[threadIdx.x] = v;
    __syncthreads();
    for (int ofs = 128; ofs > 0; ofs >>= 1) {
        if (threadIdx.x < ofs) sh[threadIdx.x] += sh[threadIdx.x + ofs];
        __syncthreads();
    }
    if (threadIdx.x == 0) partial[blockIdx.x] = sh[0];
}

__global__ __launch_bounds__(1024) void scan_top_kernel(
    int* __restrict__ partial, int nb, int* __restrict__ row_ptr, int n) {
    __shared__ int sh[1024];
    int t = threadIdx.x;
    int v = (t < nb) ? partial[t] : 0;
    sh[t] = v;
    __syncthreads();
    for (int ofs = 1; ofs < 1024; ofs <<= 1) {
        int tv = (t >= ofs) ? sh[t - ofs] : 0;
        __syncthreads();
        sh[t] += tv;
        __syncthreads();
    }
    if (t < nb) partial[t] = sh[t] - v;          // exclusive
    if (t == 1023) row_ptr[n] = sh[1023];
}

__global__ void scan_final_kernel(const int* __restrict__ cnt, const int* __restrict__ partial,
                                  int* __restrict__ row_ptr, float* __restrict__ dis, int n) {
    __shared__ int sh[256];
    int i = blockIdx.x * 256 + threadIdx.x;
    int v = (i < n) ? cnt[i] : 0;
    sh[threadIdx.x] = v;
    __syncthreads();
    for (int ofs = 1; ofs < 256; ofs <<= 1) {
        int t = 0;
        if (threadIdx.x >= ofs) t = sh[threadIdx.x - ofs];
        __syncthreads();
        if (threadIdx.x >= ofs) sh[threadIdx.x] += t;
        __syncthreads();
    }
    if (i < n) {
        row_ptr[i] = partial[blockIdx.x] + sh[threadIdx.x] - v;
        dis[i] = rsqrtf(1.0f + (float)v);
    }
}

__global__ void fill_kernel(const int* __restrict__ src, const int* __restrict__ dst,
                            const int* __restrict__ row_ptr, const int* __restrict__ rank,
                            int* __restrict__ csr_src, int E) {
    int e = blockIdx.x * blockDim.x + threadIdx.x;
    if (e >= E) return;
    csr_src[row_ptr[dst[e]] + rank[e]] = src[e];
}

// ---------------- W transpose + bf16: Wt[c][k] = bf16(W[k][c]) ---------------

__global__ void wt_kernel(const float* __restrict__ W, unsigned short* __restrict__ Wt,
                          int K, int N) {
    int idx = blockIdx.x * 256 + threadIdx.x;    // idx = c*K + k
    if (idx >= K * N) return;
    int c = idx / K, k = idx - c * K;
    Wt[idx] = f2b(W[(size_t)k * N + c]);
}

// ---------------- GEMM 1 (MFMA): G = bf16( dis .* (X[n,256] @ W1) ) ----------
// 512 thr = 8 waves (2M x 4N). Wave: 64 rows x 32 cols = 4x2 MFMA tiles.
// Block: 128 rows x 128 cols (full N). A from global f32 (cvt in reg);
// B from Wt1[col][k] bf16 (64KB, L2-resident). No LDS, no barriers.

__global__ __launch_bounds__(512) void gemm1_mfma(
    const float* __restrict__ X, const unsigned short* __restrict__ Wt,
    const float* __restrict__ dis, unsigned short* __restrict__ G, int n) {
    constexpr int K = 256;
    int lane = threadIdx.x & 63;
    int w    = threadIdx.x >> 6;
    int wm = w >> 2, wn = w & 3;
    int rowbase = blockIdx.x * 128 + wm * 64;
    int colbase = wn * 32;
    int la = lane & 15, lb = lane >> 4;

    f32x4 acc[4][2];
    #pragma unroll
    for (int m = 0; m < 4; ++m)
        #pragma unroll
        for (int nn = 0; nn < 2; ++nn) acc[m][nn] = (f32x4){0.f, 0.f, 0.f, 0.f};

    int arow[4];
    #pragma unroll
    for (int m = 0; m < 4; ++m) {
        int row = rowbase + m * 16 + la;
        arow[m] = row < n ? row : n - 1;
    }

    for (int ks = 0; ks < K / 32; ++ks) {
        int k0 = ks * 32 + lb * 8;
        F8 a[4], b[2];
        #pragma unroll
        for (int m = 0; m < 4; ++m) {
            const float* xp = X + (size_t)arow[m] * K + k0;
            float4 x0 = *(const float4*)xp;
            float4 x1 = *(const float4*)(xp + 4);
            a[m].u[0] = f2b(x0.x); a[m].u[1] = f2b(x0.y);
            a[m].u[2] = f2b(x0.z); a[m].u[3] = f2b(x0.w);
            a[m].u[4] = f2b(x1.x); a[m].u[5] = f2b(x1.y);
            a[m].u[6] = f2b(x1.z); a[m].u[7] = f2b(x1.w);
        }
        #pragma unroll
        for (int nn = 0; nn < 2; ++nn) {
            int col = colbase + nn * 16 + la;
            b[nn].q = *(const uint4*)(Wt + (size_t)col * K + k0);
        }
        #pragma unroll
        for (int m = 0; m < 4; ++m)
            #pragma unroll
            for (int nn = 0; nn < 2; ++nn)
                acc[m][nn] = __builtin_amdgcn_mfma_f32_16x16x32_bf16(
                    a[m].v, b[nn].v, acc[m][nn], 0, 0, 0);
    }

    #pragma unroll
    for (int m = 0; m < 4; ++m) {
        int r0 = rowbase + m * 16 + lb * 4;
        float dv[4];
        #pragma unroll
        for (int r = 0; r < 4; ++r) dv[r] = (r0 + r < n) ? dis[r0 + r] : 0.f;
        #pragma unroll
        for (int nn = 0; nn < 2; ++nn) {
            int col = colbase + nn * 16 + la;
            #pragma unroll
            for (int r = 0; r < 4; ++r) {
                int row = r0 + r;
                if (row < n)
                    G[(size_t)row * HID + col] = f2b(acc[m][nn][r] * dv[r]);
            }
        }
    }
}

// ---------------- GEMM 2 (MFMA): G2 = bf16( dis .* (H[n,128] @ W2) ) ---------
// 512 thr = 8 waves (4M x 2N). Wave: 64 rows x 32 cols. Block: 256 rows x 64.
// A = bf16 h1 direct loads; B = Wt2 (16KB, L1-resident).

__global__ __launch_bounds__(512) void gemm2_mfma(
    const unsigned short* __restrict__ H, const unsigned short* __restrict__ Wt,
    const float* __restrict__ dis, unsigned short* __restrict__ G, int n) {
    constexpr int K = 128;
    int lane = threadIdx.x & 63;
    int w    = threadIdx.x >> 6;
    int wm = w >> 1, wn = w & 1;
    int rowbase = blockIdx.x * 256 + wm * 64;
    int colbase = wn * 32;
    int la = lane & 15, lb = lane >> 4;

    f32x4 acc[4][2];
    #pragma unroll
    for (int m = 0; m < 4; ++m)
        #pragma unroll
        for (int nn = 0; nn < 2; ++nn) acc[m][nn] = (f32x4){0.f, 0.f, 0.f, 0.f};

    int arow[4];
    #pragma unroll
    for (int m = 0; m < 4; ++m) {
        int row = rowbase + m * 16 + la;
        arow[m] = row < n ? row : n - 1;
    }

    for (int ks = 0; ks < K / 32; ++ks) {
        int k0 = ks * 32 + lb * 8;
        F8 a[4], b[2];
        #pragma unroll
        for (int m = 0; m < 4; ++m)
            a[m].q = *(const uint4*)(H + (size_t)arow[m] * K + k0);
        #pragma unroll
        for (int nn = 0; nn < 2; ++nn) {
            int col = colbase + nn * 16 + la;
            b[nn].q = *(const uint4*)(Wt + (size_t)col * K + k0);
        }
        #pragma unroll
        for (int m = 0; m < 4; ++m)
            #pragma unroll
            for (int nn = 0; nn < 2; ++nn)
                acc[m][nn] = __builtin_amdgcn_mfma_f32_16x16x32_bf16(
                    a[m].v, b[nn].v, acc[m][nn], 0, 0, 0);
    }

    #pragma unroll
    for (int m = 0; m < 4; ++m) {
        int r0 = rowbase + m * 16 + lb * 4;
        float dv[4];
        #pragma unroll
        for (int r = 0; r < 4; ++r) dv[r] = (r0 + r < n) ? dis[r0 + r] : 0.f;
        #pragma unroll
        for (int nn = 0; nn < 2; ++nn) {
            int col = colbase + nn * 16 + la;
            #pragma unroll
            for (int r = 0; r < 4; ++r) {
                int row = r0 + r;
                if (row < n)
                    G[(size_t)row * OUT_CH + col] = f2b(acc[m][nn][r] * dv[r]);
            }
        }
    }
}

// ---------------- Aggregation 1: h1 = bf16(relu(dis .* (self+gather) + b1)) --

__global__ __launch_bounds__(256) void agg1_kernel(
    const unsigned* __restrict__ G, const int* __restrict__ row_ptr,
    const int* __restrict__ csr_src, const float* __restrict__ dis,
    const float* __restrict__ b1, unsigned* __restrict__ H, int n) {
    int wid = (blockIdx.x * blockDim.x + threadIdx.x) >> 6;
    int lane = threadIdx.x & 63;
    if (wid >= n) return;
    float2 s0 = unpack_bf16(G[(size_t)wid * 64 + lane]);   // self term
    float2 s1 = make_float2(0.f, 0.f);
    float2 s2 = make_float2(0.f, 0.f);
    float2 s3 = make_float2(0.f, 0.f);
    int beg = row_ptr[wid], end = row_ptr[wid + 1];
    for (int base = beg; base < end; base += 64) {
        int m = end - base; if (m > 64) m = 64;
        int idx = csr_src[base + (lane < m ? lane : m - 1)];
        int j = 0;
        for (; j + 4 <= m; j += 4) {
            int ia = __shfl(idx, j);
            int ib = __shfl(idx, j + 1);
            int ic = __shfl(idx, j + 2);
            int id = __shfl(idx, j + 3);
            unsigned ua = G[(size_t)ia * 64 + lane];
            unsigned ub = G[(size_t)ib * 64 + lane];
            unsigned uc = G[(size_t)ic * 64 + lane];
            unsigned ud = G[(size_t)id * 64 + lane];
            float2 va = unpack_bf16(ua); s0.x += va.x; s0.y += va.y;
            float2 vb = unpack_bf16(ub); s1.x += vb.x; s1.y += vb.y;
            float2 vc = unpack_bf16(uc); s2.x += vc.x; s2.y += vc.y;
            float2 vd = unpack_bf16(ud); s3.x += vd.x; s3.y += vd.y;
        }
        for (; j < m; ++j) {
            int ia = __shfl(idx, j);
            float2 va = unpack_bf16(G[(size_t)ia * 64 + lane]);
            s0.x += va.x; s0.y += va.y;
        }
    }
    s0.x += s1.x + s2.x + s3.x;
    s0.y += s1.y + s2.y + s3.y;
    float d = dis[wid];
    float2 bb = ((const float2*)b1)[lane];
    float o0 = fmaf(s0.x, d, bb.x); o0 = o0 > 0.f ? o0 : 0.f;
    float o1 = fmaf(s0.y, d, bb.y); o1 = o1 > 0.f ? o1 : 0.f;
    H[(size_t)wid * 64 + lane] = pack_bf16(o0, o1);
}

// ---------------- Aggregation 2: out = dis .* (self+gather) + b2 -------------

__global__ __launch_bounds__(256) void agg2_kernel(
    const unsigned short* __restrict__ G, const int* __restrict__ row_ptr,
    const int* __restrict__ csr_src, const float* __restrict__ dis,
    const float* __restrict__ b2, float* __restrict__ out, int n) {
    int wid = (blockIdx.x * blockDim.x + threadIdx.x) >> 6;
    int lane = threadIdx.x & 63;
    if (wid >= n) return;
    float s0 = bf16_to_f32(G[(size_t)wid * 64 + lane]);
    float s1 = 0.f, s2 = 0.f, s3 = 0.f;
    int beg = row_ptr[wid], end = row_ptr[wid + 1];
    for (int base = beg; base < end; base += 64) {
        int m = end - base; if (m > 64) m = 64;
        int idx = csr_src[base + (lane < m ? lane : m - 1)];
        int j = 0;
        for (; j + 4 <= m; j += 4) {
            int ia = __shfl(idx, j);
            int ib = __shfl(idx, j + 1);
            int ic = __shfl(idx, j + 2);
            int id = __shfl(idx, j + 3);
            s0 += bf16_to_f32(G[(size_t)ia * 64 + lane]);
            s1 += bf16_to_f32(G[(size_t)ib * 64 + lane]);
            s2 += bf16_to_f32(G[(size_t)ic * 64 + lane]);
            s3 += bf16_to_f32(G[(size_t)id * 64 + lane]);
        }
        for (; j < m; ++j) {
            int ia = __shfl(idx, j);
            s0 += bf16_to_f32(G[(size_t)ia * 64 + lane]);
        }
    }
    s0 += s1 + s2 + s3;
    out[(size_t)wid * 64 + lane] = fmaf(s0, dis[wid], b2[lane]);
}

// ---------------- launch ----------------

extern "C" void kernel_launch(void* const* d_in, const int* in_sizes, int n_in,
                              void* d_out, int out_size, void* d_ws, size_t ws_size,
                              hipStream_t stream) {
    const float* x  = (const float*)d_in[0];
    const int*   ei = (const int*)d_in[1];
    const float* W1 = (const float*)d_in[2];
    const float* b1 = (const float*)d_in[3];
    const float* W2 = (const float*)d_in[4];
    const float* b2 = (const float*)d_in[5];
    float* out = (float*)d_out;

    int n = in_sizes[0] / IN_CH;       // 100000
    int E = in_sizes[1] / 2;           // 1600000
    const int* srcv = ei;
    const int* dstv = ei + E;

    char* w = (char*)d_ws;
    unsigned short* g1 = (unsigned short*)w;  w += (size_t)n * HID * 2;   // 25.6 MB
    unsigned short* h1 = (unsigned short*)w;  w += (size_t)n * HID * 2;   // 25.6 MB
    unsigned short* g2 = g1;                                              // overlay
    unsigned short* wt1 = (unsigned short*)w; w += (size_t)IN_CH * HID * 2;  // 64 KB
    unsigned short* wt2 = (unsigned short*)w; w += (size_t)HID * OUT_CH * 2; // 16 KB
    int*   cnt     = (int*)w;   w += (size_t)n * 4;
    float* dis     = (float*)w; w += (size_t)n * 4;
    int*   row_ptr = (int*)w;   w += (size_t)(n + 1) * 4;
    int*   partial = (int*)w;   w += (size_t)1024 * 4;
    int*   rank    = (int*)w;   w += (size_t)E * 4;
    int*   csr     = (int*)w;   w += (size_t)E * 4;

    int nb  = (n + 255) / 256;
    int ebk = (E + 255) / 256;

    hipMemsetAsync(cnt, 0, (size_t)n * 4, stream);

    hist_kernel<<<ebk, 256, 0, stream>>>(dstv, cnt, rank, E);
    scan_partial_kernel<<<nb, 256, 0, stream>>>(cnt, partial, n);
    scan_top_kernel<<<1, 1024, 0, stream>>>(partial, nb, row_ptr, n);
    scan_final_kernel<<<nb, 256, 0, stream>>>(cnt, partial, row_ptr, dis, n);
    fill_kernel<<<ebk, 256, 0, stream>>>(srcv, dstv, row_ptr, rank, csr, E);

    wt_kernel<<<(IN_CH * HID + 255) / 256, 256, 0, stream>>>(W1, wt1, IN_CH, HID);
    wt_kernel<<<(HID * OUT_CH + 255) / 256, 256, 0, stream>>>(W2, wt2, HID, OUT_CH);

    gemm1_mfma<<<(n + 127) / 128, 512, 0, stream>>>(x, wt1, dis, g1, n);
    agg1_kernel<<<(n + 3) / 4, 256, 0, stream>>>((const unsigned*)g1, row_ptr, csr, dis, b1, (unsigned*)h1, n);
    gemm2_mfma<<<(n + 255) / 256, 512, 0, stream>>>(h1, wt2, dis, g2, n);
    agg2_kernel<<<(n + 3) / 4, 256, 0, stream>>>(g2, row_ptr, csr, dis, b2, out, n);
}

// Round 5
// 278.138 us; speedup vs baseline: 2.4611x; 1.1732x over previous
//
#include <hip/hip_runtime.h>

// ---------------------------------------------------------------------------
// GCN 2-layer forward on MI355X.
//  out = Ahat( relu( Ahat (X W1) + b1 ) W2 ) + b2,  Ahat = D^-1/2 (A+I) D^-1/2
// Factored: g = dis .* (X W);  s[i] = g[i] + sum_{e: dst=i} g[src[e]];
//           layer_out[i] = dis[i]*s[i] + b
// R5: GEMMs keep bf16 MFMA but A goes through LDS (coalesced staged loads,
//     f32->bf16 once during staging, double-buffered, pad-20 stride so
//     ds_read_b128 is 2-way = free). B direct from L2-hot Wt.
// ---------------------------------------------------------------------------

constexpr int IN_CH  = 256;
constexpr int HID    = 128;
constexpr int OUT_CH = 64;

typedef __attribute__((ext_vector_type(8))) short short8;
typedef __attribute__((ext_vector_type(4))) float f32x4;

union F8 {                       // one MFMA A/B fragment: 8 bf16
    short8 v;
    unsigned short u[8];
    uint4  q;
};

// ---- bf16 helpers (RNE) ----
__device__ inline unsigned short f2b(float f) {
    unsigned u = __float_as_uint(f);
    u += 0x7fffu + ((u >> 16) & 1u);
    return (unsigned short)(u >> 16);
}
__device__ inline unsigned pack_bf16(float a, float b) {
    unsigned ua = __float_as_uint(a); ua += 0x7fffu + ((ua >> 16) & 1u);
    unsigned ub = __float_as_uint(b); ub += 0x7fffu + ((ub >> 16) & 1u);
    return (ua >> 16) | (ub & 0xffff0000u);
}
__device__ inline float2 unpack_bf16(unsigned v) {
    return make_float2(__uint_as_float(v << 16), __uint_as_float(v & 0xffff0000u));
}
__device__ inline float bf16_to_f32(unsigned short h) {
    return __uint_as_float(((unsigned)h) << 16);
}

// ---------------- CSR build ----------------

__global__ void hist_kernel(const int* __restrict__ dst, int* __restrict__ cnt,
                            int* __restrict__ rank, int E) {
    int e = blockIdx.x * blockDim.x + threadIdx.x;
    if (e < E) rank[e] = atomicAdd(&cnt[dst[e]], 1);
}

__global__ void scan_partial_kernel(const int* __restrict__ cnt, int* __restrict__ partial, int n) {
    __shared__ int sh[256];
    int i = blockIdx.x * 256 + threadIdx.x;
    int v = (i < n) ? cnt[i] : 0;
    sh[threadIdx.x] = v;
    __syncthreads();
    for (int ofs = 128; ofs > 0; ofs >>= 1) {
        if (threadIdx.x < ofs) sh[threadIdx.x] += sh[threadIdx.x + ofs];
        __syncthreads();
    }
    if (threadIdx.x == 0) partial[blockIdx.x] = sh[0];
}

__global__ __launch_bounds__(1024) void scan_top_kernel(
    int* __restrict__ partial, int nb, int* __restrict__ row_ptr, int n) {
    __shared__ int sh[1024];
    int t = threadIdx.x;
    int v = (t < nb) ? partial[t] : 0;
    sh[t] = v;
    __syncthreads();
    for (int ofs = 1; ofs < 1024; ofs <<= 1) {
        int tv = (t >= ofs) ? sh[t - ofs] : 0;
        __syncthreads();
        sh[t] += tv;
        __syncthreads();
    }
    if (t < nb) partial[t] = sh[t] - v;          // exclusive
    if (t == 1023) row_ptr[n] = sh[1023];
}

__global__ void scan_final_kernel(const int* __restrict__ cnt, const int* __restrict__ partial,
                                  int* __restrict__ row_ptr, float* __restrict__ dis, int n) {
    __shared__ int sh[256];
    int i = blockIdx.x * 256 + threadIdx.x;
    int v = (i < n) ? cnt[i] : 0;
    sh[threadIdx.x] = v;
    __syncthreads();
    for (int ofs = 1; ofs < 256; ofs <<= 1) {
        int t = 0;
        if (threadIdx.x >= ofs) t = sh[threadIdx.x - ofs];
        __syncthreads();
        if (threadIdx.x >= ofs) sh[threadIdx.x] += t;
        __syncthreads();
    }
    if (i < n) {
        row_ptr[i] = partial[blockIdx.x] + sh[threadIdx.x] - v;
        dis[i] = rsqrtf(1.0f + (float)v);
    }
}

__global__ void fill_kernel(const int* __restrict__ src, const int* __restrict__ dst,
                            const int* __restrict__ row_ptr, const int* __restrict__ rank,
                            int* __restrict__ csr_src, int E) {
    int e = blockIdx.x * blockDim.x + threadIdx.x;
    if (e >= E) return;
    csr_src[row_ptr[dst[e]] + rank[e]] = src[e];
}

// ---------------- W transpose + bf16: Wt[c][k] = bf16(W[k][c]) ---------------

__global__ void wt_kernel(const float* __restrict__ W, unsigned short* __restrict__ Wt,
                          int K, int N) {
    int idx = blockIdx.x * 256 + threadIdx.x;    // idx = c*K + k
    if (idx >= K * N) return;
    int c = idx / K, k = idx - c * K;
    Wt[idx] = f2b(W[(size_t)k * N + c]);
}

// ---------------- GEMM 1 (MFMA + LDS): G = bf16( dis .* (X @ W1) ) -----------
// Block: 512 thr = 8 waves (2M x 4N), tile 128 rows x 128 cols, BK=32.
// A staged f32->bf16 into LDS (double buffer, stride 20 uints: b128 reads
// 2-way = free). B from Wt1[col][k] (64KB, L2-hot), loads in unrolled loop.

__global__ __launch_bounds__(512) void gemm1_mfma(
    const float* __restrict__ X, const unsigned short* __restrict__ Wt,
    const float* __restrict__ dis, unsigned short* __restrict__ G, int n) {
    constexpr int K = 256;
    constexpr int LP = 20;                    // LDS row stride in uints (80B)
    __shared__ unsigned xs[2][128 * LP];      // 10KB per buffer

    int tid  = threadIdx.x;
    int lane = tid & 63;
    int w    = tid >> 6;
    int wm = w >> 2, wn = w & 3;
    int rowbase = blockIdx.x * 128 + wm * 64;
    int colbase = wn * 32;
    int la = lane & 15, lb = lane >> 4;

    // staging coords: thread t -> row = t>>2 (0..127), chunk = t&3 (8 floats)
    int srow = tid >> 2, sch = tid & 3;
    int grow = blockIdx.x * 128 + srow;
    const float* xrow = X + (size_t)(grow < n ? grow : n - 1) * K + sch * 8;

    f32x4 acc[4][2];
    #pragma unroll
    for (int m = 0; m < 4; ++m)
        #pragma unroll
        for (int nn = 0; nn < 2; ++nn) acc[m][nn] = (f32x4){0.f, 0.f, 0.f, 0.f};

    // prologue: stage ks=0
    {
        float4 x0 = *(const float4*)(xrow);
        float4 x1 = *(const float4*)(xrow + 4);
        uint4 o;
        o.x = pack_bf16(x0.x, x0.y); o.y = pack_bf16(x0.z, x0.w);
        o.z = pack_bf16(x1.x, x1.y); o.w = pack_bf16(x1.z, x1.w);
        *(uint4*)&xs[0][srow * LP + sch * 4] = o;
    }
    __syncthreads();

    #pragma unroll
    for (int ks = 0; ks < K / 32; ++ks) {
        int cur = ks & 1;
        if (ks + 1 < K / 32) {                 // stage next k-slab into other buf
            const float* xp = xrow + (ks + 1) * 32;
            float4 x0 = *(const float4*)(xp);
            float4 x1 = *(const float4*)(xp + 4);
            uint4 o;
            o.x = pack_bf16(x0.x, x0.y); o.y = pack_bf16(x0.z, x0.w);
            o.z = pack_bf16(x1.x, x1.y); o.w = pack_bf16(x1.z, x1.w);
            *(uint4*)&xs[cur ^ 1][(srow)*LP + sch * 4] = o;
        }
        int k0 = ks * 32 + lb * 8;             // bf16 index within K
        F8 a[4], b[2];
        #pragma unroll
        for (int m = 0; m < 4; ++m)
            a[m].q = *(const uint4*)&xs[cur][(wm * 64 + m * 16 + la) * LP + lb * 4];
        #pragma unroll
        for (int nn = 0; nn < 2; ++nn) {
            int col = colbase + nn * 16 + la;
            b[nn].q = *(const uint4*)(Wt + (size_t)col * K + k0);
        }
        #pragma unroll
        for (int m = 0; m < 4; ++m)
            #pragma unroll
            for (int nn = 0; nn < 2; ++nn)
                acc[m][nn] = __builtin_amdgcn_mfma_f32_16x16x32_bf16(
                    a[m].v, b[nn].v, acc[m][nn], 0, 0, 0);
        __syncthreads();
    }

    #pragma unroll
    for (int m = 0; m < 4; ++m) {
        int r0 = rowbase + m * 16 + lb * 4;
        float dv[4];
        #pragma unroll
        for (int r = 0; r < 4; ++r) dv[r] = (r0 + r < n) ? dis[r0 + r] : 0.f;
        #pragma unroll
        for (int nn = 0; nn < 2; ++nn) {
            int col = colbase + nn * 16 + la;
            #pragma unroll
            for (int r = 0; r < 4; ++r) {
                int row = r0 + r;
                if (row < n)
                    G[(size_t)row * HID + col] = f2b(acc[m][nn][r] * dv[r]);
            }
        }
    }
}

// ---------------- GEMM 2 (MFMA + LDS): G2 = bf16( dis .* (H @ W2) ) ----------
// Block: 512 thr = 8 waves (4M x 2N), tile 256 rows x 64 cols, BK=32.
// A = bf16 h1 staged into LDS (no conversion). B = Wt2 (16KB, L1-hot).

__global__ __launch_bounds__(512) void gemm2_mfma(
    const unsigned short* __restrict__ H, const unsigned short* __restrict__ Wt,
    const float* __restrict__ dis, unsigned short* __restrict__ G, int n) {
    constexpr int K = 128;
    constexpr int LP = 20;
    __shared__ unsigned xs[2][256 * LP];      // 20KB per buffer

    int tid  = threadIdx.x;
    int lane = tid & 63;
    int w    = tid >> 6;
    int wm = w >> 1, wn = w & 1;
    int rowbase = blockIdx.x * 256 + wm * 64;
    int colbase = wn * 32;
    int la = lane & 15, lb = lane >> 4;

    const unsigned* Hu = (const unsigned*)H;   // 64 uints per row

    f32x4 acc[4][2];
    #pragma unroll
    for (int m = 0; m < 4; ++m)
        #pragma unroll
        for (int nn = 0; nn < 2; ++nn) acc[m][nn] = (f32x4){0.f, 0.f, 0.f, 0.f};

    // staging: 256 rows x 16 uints = 1024 uint4-slots; 512 thr x 2
    int sr0 = tid >> 2, sq0 = tid & 3;                 // j=0
    int sr1 = (tid + 512) >> 2, sq1 = tid & 3;         // j=1
    int g0 = blockIdx.x * 256 + sr0; g0 = g0 < n ? g0 : n - 1;
    int g1 = blockIdx.x * 256 + sr1; g1 = g1 < n ? g1 : n - 1;

    {
        *(uint4*)&xs[0][sr0 * LP + sq0 * 4] = *(const uint4*)&Hu[(size_t)g0 * 64 + sq0 * 4];
        *(uint4*)&xs[0][sr1 * LP + sq1 * 4] = *(const uint4*)&Hu[(size_t)g1 * 64 + sq1 * 4];
    }
    __syncthreads();

    #pragma unroll
    for (int ks = 0; ks < K / 32; ++ks) {
        int cur = ks & 1;
        if (ks + 1 < K / 32) {
            int kq = (ks + 1) * 16;            // uint offset of k-slab
            *(uint4*)&xs[cur ^ 1][sr0 * LP + sq0 * 4] = *(const uint4*)&Hu[(size_t)g0 * 64 + kq + sq0 * 4];
            *(uint4*)&xs[cur ^ 1][sr1 * LP + sq1 * 4] = *(const uint4*)&Hu[(size_t)g1 * 64 + kq + sq1 * 4];
        }
        int k0 = ks * 32 + lb * 8;
        F8 a[4], b[2];
        #pragma unroll
        for (int m = 0; m < 4; ++m)
            a[m].q = *(const uint4*)&xs[cur][(wm * 64 + m * 16 + la) * LP + lb * 4];
        #pragma unroll
        for (int nn = 0; nn < 2; ++nn) {
            int col = colbase + nn * 16 + la;
            b[nn].q = *(const uint4*)(Wt + (size_t)col * K + k0);
        }
        #pragma unroll
        for (int m = 0; m < 4; ++m)
            #pragma unroll
            for (int nn = 0; nn < 2; ++nn)
                acc[m][nn] = __builtin_amdgcn_mfma_f32_16x16x32_bf16(
                    a[m].v, b[nn].v, acc[m][nn], 0, 0, 0);
        __syncthreads();
    }

    #pragma unroll
    for (int m = 0; m < 4; ++m) {
        int r0 = rowbase + m * 16 + lb * 4;
        float dv[4];
        #pragma unroll
        for (int r = 0; r < 4; ++r) dv[r] = (r0 + r < n) ? dis[r0 + r] : 0.f;
        #pragma unroll
        for (int nn = 0; nn < 2; ++nn) {
            int col = colbase + nn * 16 + la;
            #pragma unroll
            for (int r = 0; r < 4; ++r) {
                int row = r0 + r;
                if (row < n)
                    G[(size_t)row * OUT_CH + col] = f2b(acc[m][nn][r] * dv[r]);
            }
        }
    }
}

// ---------------- Aggregation 1: h1 = bf16(relu(dis .* (self+gather) + b1)) --

__global__ __launch_bounds__(256) void agg1_kernel(
    const unsigned* __restrict__ G, const int* __restrict__ row_ptr,
    const int* __restrict__ csr_src, const float* __restrict__ dis,
    const float* __restrict__ b1, unsigned* __restrict__ H, int n) {
    int wid = (blockIdx.x * blockDim.x + threadIdx.x) >> 6;
    int lane = threadIdx.x & 63;
    if (wid >= n) return;
    float2 s0 = unpack_bf16(G[(size_t)wid * 64 + lane]);   // self term
    float2 s1 = make_float2(0.f, 0.f);
    float2 s2 = make_float2(0.f, 0.f);
    float2 s3 = make_float2(0.f, 0.f);
    int beg = row_ptr[wid], end = row_ptr[wid + 1];
    for (int base = beg; base < end; base += 64) {
        int m = end - base; if (m > 64) m = 64;
        int idx = csr_src[base + (lane < m ? lane : m - 1)];
        int j = 0;
        for (; j + 4 <= m; j += 4) {
            int ia = __shfl(idx, j);
            int ib = __shfl(idx, j + 1);
            int ic = __shfl(idx, j + 2);
            int id = __shfl(idx, j + 3);
            unsigned ua = G[(size_t)ia * 64 + lane];
            unsigned ub = G[(size_t)ib * 64 + lane];
            unsigned uc = G[(size_t)ic * 64 + lane];
            unsigned ud = G[(size_t)id * 64 + lane];
            float2 va = unpack_bf16(ua); s0.x += va.x; s0.y += va.y;
            float2 vb = unpack_bf16(ub); s1.x += vb.x; s1.y += vb.y;
            float2 vc = unpack_bf16(uc); s2.x += vc.x; s2.y += vc.y;
            float2 vd = unpack_bf16(ud); s3.x += vd.x; s3.y += vd.y;
        }
        for (; j < m; ++j) {
            int ia = __shfl(idx, j);
            float2 va = unpack_bf16(G[(size_t)ia * 64 + lane]);
            s0.x += va.x; s0.y += va.y;
        }
    }
    s0.x += s1.x + s2.x + s3.x;
    s0.y += s1.y + s2.y + s3.y;
    float d = dis[wid];
    float2 bb = ((const float2*)b1)[lane];
    float o0 = fmaf(s0.x, d, bb.x); o0 = o0 > 0.f ? o0 : 0.f;
    float o1 = fmaf(s0.y, d, bb.y); o1 = o1 > 0.f ? o1 : 0.f;
    H[(size_t)wid * 64 + lane] = pack_bf16(o0, o1);
}

// ---------------- Aggregation 2: out = dis .* (self+gather) + b2 -------------

__global__ __launch_bounds__(256) void agg2_kernel(
    const unsigned short* __restrict__ G, const int* __restrict__ row_ptr,
    const int* __restrict__ csr_src, const float* __restrict__ dis,
    const float* __restrict__ b2, float* __restrict__ out, int n) {
    int wid = (blockIdx.x * blockDim.x + threadIdx.x) >> 6;
    int lane = threadIdx.x & 63;
    if (wid >= n) return;
    float s0 = bf16_to_f32(G[(size_t)wid * 64 + lane]);
    float s1 = 0.f, s2 = 0.f, s3 = 0.f;
    int beg = row_ptr[wid], end = row_ptr[wid + 1];
    for (int base = beg; base < end; base += 64) {
        int m = end - base; if (m > 64) m = 64;
        int idx = csr_src[base + (lane < m ? lane : m - 1)];
        int j = 0;
        for (; j + 4 <= m; j += 4) {
            int ia = __shfl(idx, j);
            int ib = __shfl(idx, j + 1);
            int ic = __shfl(idx, j + 2);
            int id = __shfl(idx, j + 3);
            s0 += bf16_to_f32(G[(size_t)ia * 64 + lane]);
            s1 += bf16_to_f32(G[(size_t)ib * 64 + lane]);
            s2 += bf16_to_f32(G[(size_t)ic * 64 + lane]);
            s3 += bf16_to_f32(G[(size_t)id * 64 + lane]);
        }
        for (; j < m; ++j) {
            int ia = __shfl(idx, j);
            s0 += bf16_to_f32(G[(size_t)ia * 64 + lane]);
        }
    }
    s0 += s1 + s2 + s3;
    out[(size_t)wid * 64 + lane] = fmaf(s0, dis[wid], b2[lane]);
}

// ---------------- launch ----------------

extern "C" void kernel_launch(void* const* d_in, const int* in_sizes, int n_in,
                              void* d_out, int out_size, void* d_ws, size_t ws_size,
                              hipStream_t stream) {
    const float* x  = (const float*)d_in[0];
    const int*   ei = (const int*)d_in[1];
    const float* W1 = (const float*)d_in[2];
    const float* b1 = (const float*)d_in[3];
    const float* W2 = (const float*)d_in[4];
    const float* b2 = (const float*)d_in[5];
    float* out = (float*)d_out;

    int n = in_sizes[0] / IN_CH;       // 100000
    int E = in_sizes[1] / 2;           // 1600000
    const int* srcv = ei;
    const int* dstv = ei + E;

    char* w = (char*)d_ws;
    unsigned short* g1 = (unsigned short*)w;  w += (size_t)n * HID * 2;   // 25.6 MB
    unsigned short* h1 = (unsigned short*)w;  w += (size_t)n * HID * 2;   // 25.6 MB
    unsigned short* g2 = g1;                                              // overlay
    unsigned short* wt1 = (unsigned short*)w; w += (size_t)IN_CH * HID * 2;  // 64 KB
    unsigned short* wt2 = (unsigned short*)w; w += (size_t)HID * OUT_CH * 2; // 16 KB
    int*   cnt     = (int*)w;   w += (size_t)n * 4;
    float* dis     = (float*)w; w += (size_t)n * 4;
    int*   row_ptr = (int*)w;   w += (size_t)(n + 1) * 4;
    int*   partial = (int*)w;   w += (size_t)1024 * 4;
    int*   rank    = (int*)w;   w += (size_t)E * 4;
    int*   csr     = (int*)w;   w += (size_t)E * 4;

    int nb  = (n + 255) / 256;
    int ebk = (E + 255) / 256;

    hipMemsetAsync(cnt, 0, (size_t)n * 4, stream);

    hist_kernel<<<ebk, 256, 0, stream>>>(dstv, cnt, rank, E);
    scan_partial_kernel<<<nb, 256, 0, stream>>>(cnt, partial, n);
    scan_top_kernel<<<1, 1024, 0, stream>>>(partial, nb, row_ptr, n);
    scan_final_kernel<<<nb, 256, 0, stream>>>(cnt, partial, row_ptr, dis, n);
    fill_kernel<<<ebk, 256, 0, stream>>>(srcv, dstv, row_ptr, rank, csr, E);

    wt_kernel<<<(IN_CH * HID + 255) / 256, 256, 0, stream>>>(W1, wt1, IN_CH, HID);
    wt_kernel<<<(HID * OUT_CH + 255) / 256, 256, 0, stream>>>(W2, wt2, HID, OUT_CH);

    gemm1_mfma<<<(n + 127) / 128, 512, 0, stream>>>(x, wt1, dis, g1, n);
    agg1_kernel<<<(n + 3) / 4, 256, 0, stream>>>((const unsigned*)g1, row_ptr, csr, dis, b1, (unsigned*)h1, n);
    gemm2_mfma<<<(n + 255) / 256, 512, 0, stream>>>(h1, wt2, dis, g2, n);
    agg2_kernel<<<(n + 3) / 4, 256, 0, stream>>>(g2, row_ptr, csr, dis, b2, out, n);
}

// Round 6
// 243.658 us; speedup vs baseline: 2.8094x; 1.1415x over previous
//
#include <hip/hip_runtime.h>

// ---------------------------------------------------------------------------
// GCN 2-layer forward on MI355X.
//  out = Ahat( relu( Ahat (X W1) + b1 ) W2 ) + b2,  Ahat = D^-1/2 (A+I) D^-1/2
// Factored: g = dis .* (X W);  s[i] = g[i] + sum_{e: dst=i} g[src[e]];
//           layer_out[i] = dis[i]*s[i] + b
// R6: CSR build with ZERO global atomics (device atomics = memory-side RMW,
//     ~35B HBM write each; 1.6M of them cost 67us). Bucket-radix instead:
//     LDS 256-bin hist w/ local rank -> flat scan -> bucket scatter ->
//     per-bucket (512-node) LDS finalize producing row_ptr, dis, csr.
// ---------------------------------------------------------------------------

constexpr int IN_CH  = 256;
constexpr int HID    = 128;
constexpr int OUT_CH = 64;
constexpr int BUCKETS = 256;      // bucket = dst >> 9 (512 nodes per bucket)
constexpr int EPB = 8192;         // edges per block in passes A/C

typedef __attribute__((ext_vector_type(8))) short short8;
typedef __attribute__((ext_vector_type(4))) float f32x4;

union F8 {                       // one MFMA A/B fragment: 8 bf16
    short8 v;
    unsigned short u[8];
    uint4  q;
};

// ---- bf16 helpers (RNE) ----
__device__ inline unsigned short f2b(float f) {
    unsigned u = __float_as_uint(f);
    u += 0x7fffu + ((u >> 16) & 1u);
    return (unsigned short)(u >> 16);
}
__device__ inline unsigned pack_bf16(float a, float b) {
    unsigned ua = __float_as_uint(a); ua += 0x7fffu + ((ua >> 16) & 1u);
    unsigned ub = __float_as_uint(b); ub += 0x7fffu + ((ub >> 16) & 1u);
    return (ua >> 16) | (ub & 0xffff0000u);
}
__device__ inline float2 unpack_bf16(unsigned v) {
    return make_float2(__uint_as_float(v << 16), __uint_as_float(v & 0xffff0000u));
}
__device__ inline float bf16_to_f32(unsigned short h) {
    return __uint_as_float(((unsigned)h) << 16);
}

// ---------------- CSR build (bucket radix, LDS atomics only) ----------------

// A: per-block 256-bin LDS histogram; lrank = arrival index in (block,bucket).
__global__ __launch_bounds__(256) void bucket_hist(
    const int* __restrict__ dst, unsigned short* __restrict__ lrank,
    int* __restrict__ blockhist, int E, int NB) {
    __shared__ int lbin[BUCKETS];
    lbin[threadIdx.x] = 0;
    __syncthreads();
    int base = blockIdx.x * EPB;
    #pragma unroll 4
    for (int j = 0; j < EPB / 256; ++j) {
        int e = base + j * 256 + threadIdx.x;
        if (e < E) {
            int b = ((unsigned)dst[e]) >> 9;
            lrank[e] = (unsigned short)atomicAdd(&lbin[b], 1);
        }
    }
    __syncthreads();
    blockhist[threadIdx.x * NB + blockIdx.x] = lbin[threadIdx.x];   // bucket-major
}

__global__ void scan_partial_kernel(const int* __restrict__ in, int* __restrict__ partial, int len) {
    __shared__ int sh[256];
    int i = blockIdx.x * 256 + threadIdx.x;
    int v = (i < len) ? in[i] : 0;
    sh[threadIdx.x] = v;
    __syncthreads();
    for (int ofs = 128; ofs > 0; ofs >>= 1) {
        if (threadIdx.x < ofs) sh[threadIdx.x] += sh[threadIdx.x + ofs];
        __syncthreads();
    }
    if (threadIdx.x == 0) partial[blockIdx.x] = sh[0];
}

// exclusive-scans `partial` in place; writes grand total to out[L].
__global__ __launch_bounds__(1024) void scan_top_kernel(
    int* __restrict__ partial, int nb, int* __restrict__ out, int L) {
    __shared__ int sh[1024];
    int t = threadIdx.x;
    int v = (t < nb) ? partial[t] : 0;
    sh[t] = v;
    __syncthreads();
    for (int ofs = 1; ofs < 1024; ofs <<= 1) {
        int tv = (t >= ofs) ? sh[t - ofs] : 0;
        __syncthreads();
        sh[t] += tv;
        __syncthreads();
    }
    if (t < nb) partial[t] = sh[t] - v;          // exclusive
    if (t == 1023) out[L] = sh[1023];            // grand total (== E)
}

__global__ void scan_final_kernel(const int* __restrict__ in, const int* __restrict__ partial,
                                  int* __restrict__ out, int len) {
    __shared__ int sh[256];
    int i = blockIdx.x * 256 + threadIdx.x;
    int v = (i < len) ? in[i] : 0;
    sh[threadIdx.x] = v;
    __syncthreads();
    for (int ofs = 1; ofs < 256; ofs <<= 1) {
        int t = 0;
        if (threadIdx.x >= ofs) t = sh[threadIdx.x - ofs];
        __syncthreads();
        if (threadIdx.x >= ofs) sh[threadIdx.x] += t;
        __syncthreads();
    }
    if (i < len) out[i] = partial[blockIdx.x] + sh[threadIdx.x] - v;   // exclusive
}

// C: scatter edges into bucket-sorted order (no atomics).
__global__ __launch_bounds__(256) void bucket_scatter(
    const int* __restrict__ src, const int* __restrict__ dst,
    const unsigned short* __restrict__ lrank, const int* __restrict__ flatscan,
    int2* __restrict__ sorted, int E, int NB) {
    int base = blockIdx.x * EPB;
    #pragma unroll 4
    for (int j = 0; j < EPB / 256; ++j) {
        int e = base + j * 256 + threadIdx.x;
        if (e < E) {
            int d = dst[e];
            int b = ((unsigned)d) >> 9;
            int slot = flatscan[b * NB + blockIdx.x] + (int)lrank[e];
            sorted[slot] = make_int2(src[e], d);
        }
    }
}

// D: one block per bucket (512 nodes): per-node count, LDS scan, row_ptr,
// dis, and node-sorted csr placement. All atomics in LDS.
__global__ __launch_bounds__(256) void bucket_finalize(
    const int2* __restrict__ sorted, const int* __restrict__ flatscan,
    int* __restrict__ csr_src, int* __restrict__ row_ptr, float* __restrict__ dis,
    int NB, int n) {
    __shared__ int cnt[512];
    __shared__ int scn[512];
    __shared__ int cur[512];
    __shared__ int p[256];
    int b = blockIdx.x;
    int t = threadIdx.x;
    int ebeg = flatscan[b * NB];
    int eend = flatscan[(b + 1) * NB];     // b=255 -> flatscan[L] = E
    cnt[t] = 0; cnt[t + 256] = 0;
    __syncthreads();
    for (int e = ebeg + t; e < eend; e += 256)
        atomicAdd(&cnt[sorted[e].y - b * 512], 1);
    __syncthreads();
    // exclusive scan of cnt[512]: pair-sum + Hillis-Steele over 256
    int c0 = cnt[2 * t], c1 = cnt[2 * t + 1];
    int pairsum = c0 + c1;
    p[t] = pairsum;
    __syncthreads();
    for (int ofs = 1; ofs < 256; ofs <<= 1) {
        int tv = (t >= ofs) ? p[t - ofs] : 0;
        __syncthreads();
        p[t] += tv;
        __syncthreads();
    }
    int excl = p[t] - pairsum;             // exclusive pair prefix
    scn[2 * t] = excl;
    scn[2 * t + 1] = excl + c0;
    __syncthreads();
    // row_ptr / dis / cursor init
    #pragma unroll
    for (int l = t; l < 512; l += 256) {
        int node = b * 512 + l;
        if (node <= n) row_ptr[node] = ebeg + scn[l];
        if (node < n)  dis[node] = rsqrtf(1.0f + (float)cnt[l]);
        cur[l] = scn[l];
    }
    __syncthreads();
    for (int e = ebeg + t; e < eend; e += 256) {
        int2 sd = sorted[e];
        int pos = atomicAdd(&cur[sd.y - b * 512], 1);
        csr_src[ebeg + pos] = sd.x;
    }
}

// ---------------- W transpose + bf16: Wt[c][k] = bf16(W[k][c]) ---------------

__global__ void wt_kernel(const float* __restrict__ W, unsigned short* __restrict__ Wt,
                          int K, int N) {
    int idx = blockIdx.x * 256 + threadIdx.x;    // idx = c*K + k
    if (idx >= K * N) return;
    int c = idx / K, k = idx - c * K;
    Wt[idx] = f2b(W[(size_t)k * N + c]);
}

// ---------------- GEMM 1 (MFMA + LDS): G = bf16( dis .* (X @ W1) ) -----------

__global__ __launch_bounds__(512) void gemm1_mfma(
    const float* __restrict__ X, const unsigned short* __restrict__ Wt,
    const float* __restrict__ dis, unsigned short* __restrict__ G, int n) {
    constexpr int K = 256;
    constexpr int LP = 20;                    // LDS row stride in uints (80B)
    __shared__ unsigned xs[2][128 * LP];

    int tid  = threadIdx.x;
    int lane = tid & 63;
    int w    = tid >> 6;
    int wm = w >> 2, wn = w & 3;
    int rowbase = blockIdx.x * 128 + wm * 64;
    int colbase = wn * 32;
    int la = lane & 15, lb = lane >> 4;

    int srow = tid >> 2, sch = tid & 3;
    int grow = blockIdx.x * 128 + srow;
    const float* xrow = X + (size_t)(grow < n ? grow : n - 1) * K + sch * 8;

    f32x4 acc[4][2];
    #pragma unroll
    for (int m = 0; m < 4; ++m)
        #pragma unroll
        for (int nn = 0; nn < 2; ++nn) acc[m][nn] = (f32x4){0.f, 0.f, 0.f, 0.f};

    {
        float4 x0 = *(const float4*)(xrow);
        float4 x1 = *(const float4*)(xrow + 4);
        uint4 o;
        o.x = pack_bf16(x0.x, x0.y); o.y = pack_bf16(x0.z, x0.w);
        o.z = pack_bf16(x1.x, x1.y); o.w = pack_bf16(x1.z, x1.w);
        *(uint4*)&xs[0][srow * LP + sch * 4] = o;
    }
    __syncthreads();

    #pragma unroll
    for (int ks = 0; ks < K / 32; ++ks) {
        int cur = ks & 1;
        if (ks + 1 < K / 32) {
            const float* xp = xrow + (ks + 1) * 32;
            float4 x0 = *(const float4*)(xp);
            float4 x1 = *(const float4*)(xp + 4);
            uint4 o;
            o.x = pack_bf16(x0.x, x0.y); o.y = pack_bf16(x0.z, x0.w);
            o.z = pack_bf16(x1.x, x1.y); o.w = pack_bf16(x1.z, x1.w);
            *(uint4*)&xs[cur ^ 1][(srow)*LP + sch * 4] = o;
        }
        int k0 = ks * 32 + lb * 8;
        F8 a[4], b[2];
        #pragma unroll
        for (int m = 0; m < 4; ++m)
            a[m].q = *(const uint4*)&xs[cur][(wm * 64 + m * 16 + la) * LP + lb * 4];
        #pragma unroll
        for (int nn = 0; nn < 2; ++nn) {
            int col = colbase + nn * 16 + la;
            b[nn].q = *(const uint4*)(Wt + (size_t)col * K + k0);
        }
        #pragma unroll
        for (int m = 0; m < 4; ++m)
            #pragma unroll
            for (int nn = 0; nn < 2; ++nn)
                acc[m][nn] = __builtin_amdgcn_mfma_f32_16x16x32_bf16(
                    a[m].v, b[nn].v, acc[m][nn], 0, 0, 0);
        __syncthreads();
    }

    #pragma unroll
    for (int m = 0; m < 4; ++m) {
        int r0 = rowbase + m * 16 + lb * 4;
        float dv[4];
        #pragma unroll
        for (int r = 0; r < 4; ++r) dv[r] = (r0 + r < n) ? dis[r0 + r] : 0.f;
        #pragma unroll
        for (int nn = 0; nn < 2; ++nn) {
            int col = colbase + nn * 16 + la;
            #pragma unroll
            for (int r = 0; r < 4; ++r) {
                int row = r0 + r;
                if (row < n)
                    G[(size_t)row * HID + col] = f2b(acc[m][nn][r] * dv[r]);
            }
        }
    }
}

// ---------------- GEMM 2 (MFMA + LDS): G2 = bf16( dis .* (H @ W2) ) ----------

__global__ __launch_bounds__(512) void gemm2_mfma(
    const unsigned short* __restrict__ H, const unsigned short* __restrict__ Wt,
    const float* __restrict__ dis, unsigned short* __restrict__ G, int n) {
    constexpr int K = 128;
    constexpr int LP = 20;
    __shared__ unsigned xs[2][256 * LP];

    int tid  = threadIdx.x;
    int lane = tid & 63;
    int w    = tid >> 6;
    int wm = w >> 1, wn = w & 1;
    int rowbase = blockIdx.x * 256 + wm * 64;
    int colbase = wn * 32;
    int la = lane & 15, lb = lane >> 4;

    const unsigned* Hu = (const unsigned*)H;

    f32x4 acc[4][2];
    #pragma unroll
    for (int m = 0; m < 4; ++m)
        #pragma unroll
        for (int nn = 0; nn < 2; ++nn) acc[m][nn] = (f32x4){0.f, 0.f, 0.f, 0.f};

    int sr0 = tid >> 2, sq0 = tid & 3;
    int sr1 = (tid + 512) >> 2, sq1 = tid & 3;
    int g0 = blockIdx.x * 256 + sr0; g0 = g0 < n ? g0 : n - 1;
    int g1 = blockIdx.x * 256 + sr1; g1 = g1 < n ? g1 : n - 1;

    {
        *(uint4*)&xs[0][sr0 * LP + sq0 * 4] = *(const uint4*)&Hu[(size_t)g0 * 64 + sq0 * 4];
        *(uint4*)&xs[0][sr1 * LP + sq1 * 4] = *(const uint4*)&Hu[(size_t)g1 * 64 + sq1 * 4];
    }
    __syncthreads();

    #pragma unroll
    for (int ks = 0; ks < K / 32; ++ks) {
        int cur = ks & 1;
        if (ks + 1 < K / 32) {
            int kq = (ks + 1) * 16;
            *(uint4*)&xs[cur ^ 1][sr0 * LP + sq0 * 4] = *(const uint4*)&Hu[(size_t)g0 * 64 + kq + sq0 * 4];
            *(uint4*)&xs[cur ^ 1][sr1 * LP + sq1 * 4] = *(const uint4*)&Hu[(size_t)g1 * 64 + kq + sq1 * 4];
        }
        int k0 = ks * 32 + lb * 8;
        F8 a[4], b[2];
        #pragma unroll
        for (int m = 0; m < 4; ++m)
            a[m].q = *(const uint4*)&xs[cur][(wm * 64 + m * 16 + la) * LP + lb * 4];
        #pragma unroll
        for (int nn = 0; nn < 2; ++nn) {
            int col = colbase + nn * 16 + la;
            b[nn].q = *(const uint4*)(Wt + (size_t)col * K + k0);
        }
        #pragma unroll
        for (int m = 0; m < 4; ++m)
            #pragma unroll
            for (int nn = 0; nn < 2; ++nn)
                acc[m][nn] = __builtin_amdgcn_mfma_f32_16x16x32_bf16(
                    a[m].v, b[nn].v, acc[m][nn], 0, 0, 0);
        __syncthreads();
    }

    #pragma unroll
    for (int m = 0; m < 4; ++m) {
        int r0 = rowbase + m * 16 + lb * 4;
        float dv[4];
        #pragma unroll
        for (int r = 0; r < 4; ++r) dv[r] = (r0 + r < n) ? dis[r0 + r] : 0.f;
        #pragma unroll
        for (int nn = 0; nn < 2; ++nn) {
            int col = colbase + nn * 16 + la;
            #pragma unroll
            for (int r = 0; r < 4; ++r) {
                int row = r0 + r;
                if (row < n)
                    G[(size_t)row * OUT_CH + col] = f2b(acc[m][nn][r] * dv[r]);
            }
        }
    }
}

// ---------------- Aggregation 1: h1 = bf16(relu(dis .* (self+gather) + b1)) --

__global__ __launch_bounds__(256) void agg1_kernel(
    const unsigned* __restrict__ G, const int* __restrict__ row_ptr,
    const int* __restrict__ csr_src, const float* __restrict__ dis,
    const float* __restrict__ b1, unsigned* __restrict__ H, int n) {
    int wid = (blockIdx.x * blockDim.x + threadIdx.x) >> 6;
    int lane = threadIdx.x & 63;
    if (wid >= n) return;
    float2 s0 = unpack_bf16(G[(size_t)wid * 64 + lane]);   // self term
    float2 s1 = make_float2(0.f, 0.f);
    float2 s2 = make_float2(0.f, 0.f);
    float2 s3 = make_float2(0.f, 0.f);
    int beg = row_ptr[wid], end = row_ptr[wid + 1];
    for (int base = beg; base < end; base += 64) {
        int m = end - base; if (m > 64) m = 64;
        int idx = csr_src[base + (lane < m ? lane : m - 1)];
        int j = 0;
        for (; j + 4 <= m; j += 4) {
            int ia = __shfl(idx, j);
            int ib = __shfl(idx, j + 1);
            int ic = __shfl(idx, j + 2);
            int id = __shfl(idx, j + 3);
            unsigned ua = G[(size_t)ia * 64 + lane];
            unsigned ub = G[(size_t)ib * 64 + lane];
            unsigned uc = G[(size_t)ic * 64 + lane];
            unsigned ud = G[(size_t)id * 64 + lane];
            float2 va = unpack_bf16(ua); s0.x += va.x; s0.y += va.y;
            float2 vb = unpack_bf16(ub); s1.x += vb.x; s1.y += vb.y;
            float2 vc = unpack_bf16(uc); s2.x += vc.x; s2.y += vc.y;
            float2 vd = unpack_bf16(ud); s3.x += vd.x; s3.y += vd.y;
        }
        for (; j < m; ++j) {
            int ia = __shfl(idx, j);
            float2 va = unpack_bf16(G[(size_t)ia * 64 + lane]);
            s0.x += va.x; s0.y += va.y;
        }
    }
    s0.x += s1.x + s2.x + s3.x;
    s0.y += s1.y + s2.y + s3.y;
    float d = dis[wid];
    float2 bb = ((const float2*)b1)[lane];
    float o0 = fmaf(s0.x, d, bb.x); o0 = o0 > 0.f ? o0 : 0.f;
    float o1 = fmaf(s0.y, d, bb.y); o1 = o1 > 0.f ? o1 : 0.f;
    H[(size_t)wid * 64 + lane] = pack_bf16(o0, o1);
}

// ---------------- Aggregation 2: out = dis .* (self+gather) + b2 -------------

__global__ __launch_bounds__(256) void agg2_kernel(
    const unsigned short* __restrict__ G, const int* __restrict__ row_ptr,
    const int* __restrict__ csr_src, const float* __restrict__ dis,
    const float* __restrict__ b2, float* __restrict__ out, int n) {
    int wid = (blockIdx.x * blockDim.x + threadIdx.x) >> 6;
    int lane = threadIdx.x & 63;
    if (wid >= n) return;
    float s0 = bf16_to_f32(G[(size_t)wid * 64 + lane]);
    float s1 = 0.f, s2 = 0.f, s3 = 0.f;
    int beg = row_ptr[wid], end = row_ptr[wid + 1];
    for (int base = beg; base < end; base += 64) {
        int m = end - base; if (m > 64) m = 64;
        int idx = csr_src[base + (lane < m ? lane : m - 1)];
        int j = 0;
        for (; j + 4 <= m; j += 4) {
            int ia = __shfl(idx, j);
            int ib = __shfl(idx, j + 1);
            int ic = __shfl(idx, j + 2);
            int id = __shfl(idx, j + 3);
            s0 += bf16_to_f32(G[(size_t)ia * 64 + lane]);
            s1 += bf16_to_f32(G[(size_t)ib * 64 + lane]);
            s2 += bf16_to_f32(G[(size_t)ic * 64 + lane]);
            s3 += bf16_to_f32(G[(size_t)id * 64 + lane]);
        }
        for (; j < m; ++j) {
            int ia = __shfl(idx, j);
            s0 += bf16_to_f32(G[(size_t)ia * 64 + lane]);
        }
    }
    s0 += s1 + s2 + s3;
    out[(size_t)wid * 64 + lane] = fmaf(s0, dis[wid], b2[lane]);
}

// ---------------- launch ----------------

extern "C" void kernel_launch(void* const* d_in, const int* in_sizes, int n_in,
                              void* d_out, int out_size, void* d_ws, size_t ws_size,
                              hipStream_t stream) {
    const float* x  = (const float*)d_in[0];
    const int*   ei = (const int*)d_in[1];
    const float* W1 = (const float*)d_in[2];
    const float* b1 = (const float*)d_in[3];
    const float* W2 = (const float*)d_in[4];
    const float* b2 = (const float*)d_in[5];
    float* out = (float*)d_out;

    int n = in_sizes[0] / IN_CH;       // 100000
    int E = in_sizes[1] / 2;           // 1600000
    const int* srcv = ei;
    const int* dstv = ei + E;

    int NB = (E + EPB - 1) / EPB;      // 196 edge-blocks
    int L  = BUCKETS * NB;             // flat (bucket,block) matrix size

    char* w = (char*)d_ws;
    unsigned short* g1 = (unsigned short*)w;  w += (size_t)n * HID * 2;   // 25.6 MB
    unsigned short* h1 = (unsigned short*)w;  w += (size_t)n * HID * 2;   // 25.6 MB
    unsigned short* g2 = g1;                                              // overlay
    unsigned short* wt1 = (unsigned short*)w; w += (size_t)IN_CH * HID * 2;
    unsigned short* wt2 = (unsigned short*)w; w += (size_t)HID * OUT_CH * 2;
    unsigned short* lrank = (unsigned short*)w; w += (size_t)E * 2;       // 3.2 MB
    int*   blockhist = (int*)w; w += (size_t)L * 4;                       // 200 KB
    int*   flatscan  = (int*)w; w += (size_t)(L + 1) * 4;
    int*   partial   = (int*)w; w += (size_t)1024 * 4;
    int2*  sorted    = (int2*)w; w += (size_t)E * 8;                      // 12.8 MB
    int*   csr       = (int*)w; w += (size_t)E * 4;                       // 6.4 MB
    int*   row_ptr   = (int*)w; w += (size_t)(n + 1) * 4;
    float* dis       = (float*)w; w += (size_t)n * 4;

    int nb2 = (L + 255) / 256;         // scan blocks over flat matrix

    bucket_hist<<<NB, 256, 0, stream>>>(dstv, lrank, blockhist, E, NB);
    scan_partial_kernel<<<nb2, 256, 0, stream>>>(blockhist, partial, L);
    scan_top_kernel<<<1, 1024, 0, stream>>>(partial, nb2, flatscan, L);
    scan_final_kernel<<<nb2, 256, 0, stream>>>(blockhist, partial, flatscan, L);
    bucket_scatter<<<NB, 256, 0, stream>>>(srcv, dstv, lrank, flatscan, sorted, E, NB);
    bucket_finalize<<<BUCKETS, 256, 0, stream>>>(sorted, flatscan, csr, row_ptr, dis, NB, n);

    wt_kernel<<<(IN_CH * HID + 255) / 256, 256, 0, stream>>>(W1, wt1, IN_CH, HID);
    wt_kernel<<<(HID * OUT_CH + 255) / 256, 256, 0, stream>>>(W2, wt2, HID, OUT_CH);

    gemm1_mfma<<<(n + 127) / 128, 512, 0, stream>>>(x, wt1, dis, g1, n);
    agg1_kernel<<<(n + 3) / 4, 256, 0, stream>>>((const unsigned*)g1, row_ptr, csr, dis, b1, (unsigned*)h1, n);
    gemm2_mfma<<<(n + 255) / 256, 512, 0, stream>>>(h1, wt2, dis, g2, n);
    agg2_kernel<<<(n + 3) / 4, 256, 0, stream>>>(g2, row_ptr, csr, dis, b2, out, n);
}

// Round 7
// 222.316 us; speedup vs baseline: 3.0791x; 1.0960x over previous
//
#include <hip/hip_runtime.h>

// ---------------------------------------------------------------------------
// GCN 2-layer forward on MI355X.
//  out = Ahat( relu( Ahat (X W1) + b1 ) W2 ) + b2,  Ahat = D^-1/2 (A+I) D^-1/2
// Factored: g = dis .* (X W);  s[i] = g[i] + sum_{e: dst=i} g[src[e]];
//           layer_out[i] = dis[i]*s[i] + b
// R7: agg kernels half-wave split (2 edges/wave-step, 8 gathers in flight,
//     shfl_xor(32) reduce). CSR build retuned: EPB=4096, 256-node buckets
//     (more blocks/CU), sorted packed to one int ((ldst<<24)|src).
// ---------------------------------------------------------------------------

constexpr int IN_CH  = 256;
constexpr int HID    = 128;
constexpr int OUT_CH = 64;
constexpr int EPB = 4096;         // edges per block in hist/scatter

typedef __attribute__((ext_vector_type(8))) short short8;
typedef __attribute__((ext_vector_type(4))) float f32x4;

union F8 {                       // one MFMA A/B fragment: 8 bf16
    short8 v;
    unsigned short u[8];
    uint4  q;
};

// ---- bf16 helpers (RNE) ----
__device__ inline unsigned short f2b(float f) {
    unsigned u = __float_as_uint(f);
    u += 0x7fffu + ((u >> 16) & 1u);
    return (unsigned short)(u >> 16);
}
__device__ inline unsigned pack_bf16(float a, float b) {
    unsigned ua = __float_as_uint(a); ua += 0x7fffu + ((ua >> 16) & 1u);
    unsigned ub = __float_as_uint(b); ub += 0x7fffu + ((ub >> 16) & 1u);
    return (ua >> 16) | (ub & 0xffff0000u);
}
__device__ inline float2 unpack_bf16(unsigned v) {
    return make_float2(__uint_as_float(v << 16), __uint_as_float(v & 0xffff0000u));
}

// ---------------- CSR build (bucket radix, LDS atomics only) ----------------
// bucket = dst >> 8 (256 nodes/bucket), NBUCK = ceil(n/256) passed runtime.

__global__ __launch_bounds__(256) void bucket_hist(
    const int* __restrict__ dst, unsigned short* __restrict__ lrank,
    int* __restrict__ blockhist, int E, int NB, int NBUCK) {
    __shared__ int lbin[512];
    for (int l = threadIdx.x; l < 512; l += 256) lbin[l] = 0;
    __syncthreads();
    int base = blockIdx.x * EPB;
    #pragma unroll 4
    for (int j = 0; j < EPB / 256; ++j) {
        int e = base + j * 256 + threadIdx.x;
        if (e < E) {
            int b = ((unsigned)dst[e]) >> 8;
            lrank[e] = (unsigned short)atomicAdd(&lbin[b], 1);
        }
    }
    __syncthreads();
    for (int l = threadIdx.x; l < NBUCK; l += 256)
        blockhist[l * NB + blockIdx.x] = lbin[l];   // bucket-major
}

__global__ void scan_partial_kernel(const int* __restrict__ in, int* __restrict__ partial, int len) {
    __shared__ int sh[256];
    int i = blockIdx.x * 256 + threadIdx.x;
    int v = (i < len) ? in[i] : 0;
    sh[threadIdx.x] = v;
    __syncthreads();
    for (int ofs = 128; ofs > 0; ofs >>= 1) {
        if (threadIdx.x < ofs) sh[threadIdx.x] += sh[threadIdx.x + ofs];
        __syncthreads();
    }
    if (threadIdx.x == 0) partial[blockIdx.x] = sh[0];
}

__global__ __launch_bounds__(1024) void scan_top_kernel(
    int* __restrict__ partial, int nb, int* __restrict__ out, int L) {
    __shared__ int sh[1024];
    int t = threadIdx.x;
    int v = (t < nb) ? partial[t] : 0;
    sh[t] = v;
    __syncthreads();
    for (int ofs = 1; ofs < 1024; ofs <<= 1) {
        int tv = (t >= ofs) ? sh[t - ofs] : 0;
        __syncthreads();
        sh[t] += tv;
        __syncthreads();
    }
    if (t < nb) partial[t] = sh[t] - v;          // exclusive
    if (t == 1023) out[L] = sh[1023];            // grand total (== E)
}

__global__ void scan_final_kernel(const int* __restrict__ in, const int* __restrict__ partial,
                                  int* __restrict__ out, int len) {
    __shared__ int sh[256];
    int i = blockIdx.x * 256 + threadIdx.x;
    int v = (i < len) ? in[i] : 0;
    sh[threadIdx.x] = v;
    __syncthreads();
    for (int ofs = 1; ofs < 256; ofs <<= 1) {
        int t = 0;
        if (threadIdx.x >= ofs) t = sh[threadIdx.x - ofs];
        __syncthreads();
        if (threadIdx.x >= ofs) sh[threadIdx.x] += t;
        __syncthreads();
    }
    if (i < len) out[i] = partial[blockIdx.x] + sh[threadIdx.x] - v;   // exclusive
}

// scatter edges into bucket-sorted order: packed (ldst<<24)|src (src < 2^24).
__global__ __launch_bounds__(256) void bucket_scatter(
    const int* __restrict__ src, const int* __restrict__ dst,
    const unsigned short* __restrict__ lrank, const int* __restrict__ flatscan,
    unsigned* __restrict__ sorted, int E, int NB) {
    int base = blockIdx.x * EPB;
    #pragma unroll 4
    for (int j = 0; j < EPB / 256; ++j) {
        int e = base + j * 256 + threadIdx.x;
        if (e < E) {
            int d = dst[e];
            int b = ((unsigned)d) >> 8;
            int slot = flatscan[b * NB + blockIdx.x] + (int)lrank[e];
            sorted[slot] = (((unsigned)(d & 255)) << 24) | (unsigned)src[e];
        }
    }
}

// one block per bucket (256 nodes): count, LDS scan, row_ptr, dis, csr place.
__global__ __launch_bounds__(256) void bucket_finalize(
    const unsigned* __restrict__ sorted, const int* __restrict__ flatscan,
    int* __restrict__ csr_src, int* __restrict__ row_ptr, float* __restrict__ dis,
    int NB, int n) {
    __shared__ int cnt[256];
    __shared__ int sh[256];
    __shared__ int cur[256];
    int b = blockIdx.x;
    int t = threadIdx.x;
    int ebeg = flatscan[b * NB];
    int eend = flatscan[(b + 1) * NB];     // last bucket -> flatscan[L] = E
    cnt[t] = 0;
    __syncthreads();
    for (int e = ebeg + t; e < eend; e += 256)
        atomicAdd(&cnt[sorted[e] >> 24], 1);
    __syncthreads();
    int v = cnt[t];
    sh[t] = v;
    __syncthreads();
    for (int ofs = 1; ofs < 256; ofs <<= 1) {
        int tv = (t >= ofs) ? sh[t - ofs] : 0;
        __syncthreads();
        sh[t] += tv;
        __syncthreads();
    }
    int excl = sh[t] - v;                   // exclusive prefix within bucket
    int node = b * 256 + t;
    if (node <= n) row_ptr[node] = ebeg + excl;
    if (node < n)  dis[node] = rsqrtf(1.0f + (float)v);
    cur[t] = excl;
    __syncthreads();
    for (int e = ebeg + t; e < eend; e += 256) {
        unsigned s = sorted[e];
        int pos = atomicAdd(&cur[s >> 24], 1);
        csr_src[ebeg + pos] = (int)(s & 0xFFFFFFu);
    }
}

// ---------------- W transpose + bf16: Wt[c][k] = bf16(W[k][c]) ---------------

__global__ void wt_kernel(const float* __restrict__ W, unsigned short* __restrict__ Wt,
                          int K, int N) {
    int idx = blockIdx.x * 256 + threadIdx.x;    // idx = c*K + k
    if (idx >= K * N) return;
    int c = idx / K, k = idx - c * K;
    Wt[idx] = f2b(W[(size_t)k * N + c]);
}

// ---------------- GEMM 1 (MFMA + LDS): G = bf16( dis .* (X @ W1) ) -----------

__global__ __launch_bounds__(512) void gemm1_mfma(
    const float* __restrict__ X, const unsigned short* __restrict__ Wt,
    const float* __restrict__ dis, unsigned short* __restrict__ G, int n) {
    constexpr int K = 256;
    constexpr int LP = 20;                    // LDS row stride in uints (80B)
    __shared__ unsigned xs[2][128 * LP];

    int tid  = threadIdx.x;
    int lane = tid & 63;
    int w    = tid >> 6;
    int wm = w >> 2, wn = w & 3;
    int rowbase = blockIdx.x * 128 + wm * 64;
    int colbase = wn * 32;
    int la = lane & 15, lb = lane >> 4;

    int srow = tid >> 2, sch = tid & 3;
    int grow = blockIdx.x * 128 + srow;
    const float* xrow = X + (size_t)(grow < n ? grow : n - 1) * K + sch * 8;

    f32x4 acc[4][2];
    #pragma unroll
    for (int m = 0; m < 4; ++m)
        #pragma unroll
        for (int nn = 0; nn < 2; ++nn) acc[m][nn] = (f32x4){0.f, 0.f, 0.f, 0.f};

    {
        float4 x0 = *(const float4*)(xrow);
        float4 x1 = *(const float4*)(xrow + 4);
        uint4 o;
        o.x = pack_bf16(x0.x, x0.y); o.y = pack_bf16(x0.z, x0.w);
        o.z = pack_bf16(x1.x, x1.y); o.w = pack_bf16(x1.z, x1.w);
        *(uint4*)&xs[0][srow * LP + sch * 4] = o;
    }
    __syncthreads();

    #pragma unroll
    for (int ks = 0; ks < K / 32; ++ks) {
        int cur = ks & 1;
        if (ks + 1 < K / 32) {
            const float* xp = xrow + (ks + 1) * 32;
            float4 x0 = *(const float4*)(xp);
            float4 x1 = *(const float4*)(xp + 4);
            uint4 o;
            o.x = pack_bf16(x0.x, x0.y); o.y = pack_bf16(x0.z, x0.w);
            o.z = pack_bf16(x1.x, x1.y); o.w = pack_bf16(x1.z, x1.w);
            *(uint4*)&xs[cur ^ 1][(srow)*LP + sch * 4] = o;
        }
        int k0 = ks * 32 + lb * 8;
        F8 a[4], b[2];
        #pragma unroll
        for (int m = 0; m < 4; ++m)
            a[m].q = *(const uint4*)&xs[cur][(wm * 64 + m * 16 + la) * LP + lb * 4];
        #pragma unroll
        for (int nn = 0; nn < 2; ++nn) {
            int col = colbase + nn * 16 + la;
            b[nn].q = *(const uint4*)(Wt + (size_t)col * K + k0);
        }
        #pragma unroll
        for (int m = 0; m < 4; ++m)
            #pragma unroll
            for (int nn = 0; nn < 2; ++nn)
                acc[m][nn] = __builtin_amdgcn_mfma_f32_16x16x32_bf16(
                    a[m].v, b[nn].v, acc[m][nn], 0, 0, 0);
        __syncthreads();
    }

    #pragma unroll
    for (int m = 0; m < 4; ++m) {
        int r0 = rowbase + m * 16 + lb * 4;
        float dv[4];
        #pragma unroll
        for (int r = 0; r < 4; ++r) dv[r] = (r0 + r < n) ? dis[r0 + r] : 0.f;
        #pragma unroll
        for (int nn = 0; nn < 2; ++nn) {
            int col = colbase + nn * 16 + la;
            #pragma unroll
            for (int r = 0; r < 4; ++r) {
                int row = r0 + r;
                if (row < n)
                    G[(size_t)row * HID + col] = f2b(acc[m][nn][r] * dv[r]);
            }
        }
    }
}

// ---------------- GEMM 2 (MFMA + LDS): G2 = bf16( dis .* (H @ W2) ) ----------

__global__ __launch_bounds__(512) void gemm2_mfma(
    const unsigned short* __restrict__ H, const unsigned short* __restrict__ Wt,
    const float* __restrict__ dis, unsigned short* __restrict__ G, int n) {
    constexpr int K = 128;
    constexpr int LP = 20;
    __shared__ unsigned xs[2][256 * LP];

    int tid  = threadIdx.x;
    int lane = tid & 63;
    int w    = tid >> 6;
    int wm = w >> 1, wn = w & 1;
    int rowbase = blockIdx.x * 256 + wm * 64;
    int colbase = wn * 32;
    int la = lane & 15, lb = lane >> 4;

    const unsigned* Hu = (const unsigned*)H;

    f32x4 acc[4][2];
    #pragma unroll
    for (int m = 0; m < 4; ++m)
        #pragma unroll
        for (int nn = 0; nn < 2; ++nn) acc[m][nn] = (f32x4){0.f, 0.f, 0.f, 0.f};

    int sr0 = tid >> 2, sq0 = tid & 3;
    int sr1 = (tid + 512) >> 2, sq1 = tid & 3;
    int g0 = blockIdx.x * 256 + sr0; g0 = g0 < n ? g0 : n - 1;
    int g1 = blockIdx.x * 256 + sr1; g1 = g1 < n ? g1 : n - 1;

    {
        *(uint4*)&xs[0][sr0 * LP + sq0 * 4] = *(const uint4*)&Hu[(size_t)g0 * 64 + sq0 * 4];
        *(uint4*)&xs[0][sr1 * LP + sq1 * 4] = *(const uint4*)&Hu[(size_t)g1 * 64 + sq1 * 4];
    }
    __syncthreads();

    #pragma unroll
    for (int ks = 0; ks < K / 32; ++ks) {
        int cur = ks & 1;
        if (ks + 1 < K / 32) {
            int kq = (ks + 1) * 16;
            *(uint4*)&xs[cur ^ 1][sr0 * LP + sq0 * 4] = *(const uint4*)&Hu[(size_t)g0 * 64 + kq + sq0 * 4];
            *(uint4*)&xs[cur ^ 1][sr1 * LP + sq1 * 4] = *(const uint4*)&Hu[(size_t)g1 * 64 + kq + sq1 * 4];
        }
        int k0 = ks * 32 + lb * 8;
        F8 a[4], b[2];
        #pragma unroll
        for (int m = 0; m < 4; ++m)
            a[m].q = *(const uint4*)&xs[cur][(wm * 64 + m * 16 + la) * LP + lb * 4];
        #pragma unroll
        for (int nn = 0; nn < 2; ++nn) {
            int col = colbase + nn * 16 + la;
            b[nn].q = *(const uint4*)(Wt + (size_t)col * K + k0);
        }
        #pragma unroll
        for (int m = 0; m < 4; ++m)
            #pragma unroll
            for (int nn = 0; nn < 2; ++nn)
                acc[m][nn] = __builtin_amdgcn_mfma_f32_16x16x32_bf16(
                    a[m].v, b[nn].v, acc[m][nn], 0, 0, 0);
        __syncthreads();
    }

    #pragma unroll
    for (int m = 0; m < 4; ++m) {
        int r0 = rowbase + m * 16 + lb * 4;
        float dv[4];
        #pragma unroll
        for (int r = 0; r < 4; ++r) dv[r] = (r0 + r < n) ? dis[r0 + r] : 0.f;
        #pragma unroll
        for (int nn = 0; nn < 2; ++nn) {
            int col = colbase + nn * 16 + la;
            #pragma unroll
            for (int r = 0; r < 4; ++r) {
                int row = r0 + r;
                if (row < n)
                    G[(size_t)row * OUT_CH + col] = f2b(acc[m][nn][r] * dv[r]);
            }
        }
    }
}

// ---------------- Aggregation 1: h1 = bf16(relu(dis .* (self+gather) + b1)) --
// One wave per node, HALF-WAVE per edge: lanes 0-31 take even edges, 32-63
// odd edges (uint2 = 4ch per lane, 256B/row still coalesced). 4-deep unroll
// -> 8 gathers in flight. Cross-half shfl_xor(32) reduce at the end.

__global__ __launch_bounds__(256) void agg1_kernel(
    const unsigned* __restrict__ G, const int* __restrict__ row_ptr,
    const int* __restrict__ csr_src, const float* __restrict__ dis,
    const float* __restrict__ b1, unsigned* __restrict__ H, int n) {
    int wid = (blockIdx.x * blockDim.x + threadIdx.x) >> 6;
    int lane = threadIdx.x & 63;
    if (wid >= n) return;
    int half = lane >> 5, hl = lane & 31;
    const uint2* Gv = (const uint2*)G;           // row = 32 uint2
    float4 s0 = {0,0,0,0}, s1 = {0,0,0,0}, s2 = {0,0,0,0}, s3 = {0,0,0,0};
    int beg = row_ptr[wid], end = row_ptr[wid + 1];
    for (int base = beg; base < end; base += 64) {
        int m = end - base; if (m > 64) m = 64;
        int idx = csr_src[base + (lane < m ? lane : m - 1)];
        int j = 0;
        for (; j + 8 <= m; j += 8) {
            int i0 = __shfl(idx, j + 0 + half);
            int i1 = __shfl(idx, j + 2 + half);
            int i2 = __shfl(idx, j + 4 + half);
            int i3 = __shfl(idx, j + 6 + half);
            uint2 u0 = Gv[(size_t)i0 * 32 + hl];
            uint2 u1 = Gv[(size_t)i1 * 32 + hl];
            uint2 u2 = Gv[(size_t)i2 * 32 + hl];
            uint2 u3 = Gv[(size_t)i3 * 32 + hl];
            float2 a, b;
            a = unpack_bf16(u0.x); b = unpack_bf16(u0.y);
            s0.x += a.x; s0.y += a.y; s0.z += b.x; s0.w += b.y;
            a = unpack_bf16(u1.x); b = unpack_bf16(u1.y);
            s1.x += a.x; s1.y += a.y; s1.z += b.x; s1.w += b.y;
            a = unpack_bf16(u2.x); b = unpack_bf16(u2.y);
            s2.x += a.x; s2.y += a.y; s2.z += b.x; s2.w += b.y;
            a = unpack_bf16(u3.x); b = unpack_bf16(u3.y);
            s3.x += a.x; s3.y += a.y; s3.z += b.x; s3.w += b.y;
        }
        for (; j < m; j += 2) {
            int rem = m - j;
            int ii = __shfl(idx, j + (rem > 1 ? half : 0));
            if (half == 0 || rem > 1) {
                uint2 u = Gv[(size_t)ii * 32 + hl];
                float2 a = unpack_bf16(u.x), b = unpack_bf16(u.y);
                s0.x += a.x; s0.y += a.y; s0.z += b.x; s0.w += b.y;
            }
        }
    }
    s0.x += s1.x + s2.x + s3.x;
    s0.y += s1.y + s2.y + s3.y;
    s0.z += s1.z + s2.z + s3.z;
    s0.w += s1.w + s2.w + s3.w;
    s0.x += __shfl_xor(s0.x, 32);
    s0.y += __shfl_xor(s0.y, 32);
    s0.z += __shfl_xor(s0.z, 32);
    s0.w += __shfl_xor(s0.w, 32);
    uint2 su = Gv[(size_t)wid * 32 + hl];        // self term
    float2 a = unpack_bf16(su.x), b = unpack_bf16(su.y);
    s0.x += a.x; s0.y += a.y; s0.z += b.x; s0.w += b.y;
    float d = dis[wid];
    float4 bb = ((const float4*)b1)[hl];
    float o0 = fmaxf(fmaf(s0.x, d, bb.x), 0.f);
    float o1 = fmaxf(fmaf(s0.y, d, bb.y), 0.f);
    float o2 = fmaxf(fmaf(s0.z, d, bb.z), 0.f);
    float o3 = fmaxf(fmaf(s0.w, d, bb.w), 0.f);
    if (half == 0) {
        uint2 ou;
        ou.x = pack_bf16(o0, o1);
        ou.y = pack_bf16(o2, o3);
        ((uint2*)H)[(size_t)wid * 32 + hl] = ou;
    }
}

// ---------------- Aggregation 2: out = dis .* (self+gather) + b2 -------------
// Same half-wave structure; row = 32 uints (64 bf16 ch), lane owns 2 ch.

__global__ __launch_bounds__(256) void agg2_kernel(
    const unsigned short* __restrict__ G, const int* __restrict__ row_ptr,
    const int* __restrict__ csr_src, const float* __restrict__ dis,
    const float* __restrict__ b2, float* __restrict__ out, int n) {
    int wid = (blockIdx.x * blockDim.x + threadIdx.x) >> 6;
    int lane = threadIdx.x & 63;
    if (wid >= n) return;
    int half = lane >> 5, hl = lane & 31;
    const unsigned* Gu = (const unsigned*)G;     // row = 32 uints
    float2 s0 = {0,0}, s1 = {0,0}, s2 = {0,0}, s3 = {0,0};
    int beg = row_ptr[wid], end = row_ptr[wid + 1];
    for (int base = beg; base < end; base += 64) {
        int m = end - base; if (m > 64) m = 64;
        int idx = csr_src[base + (lane < m ? lane : m - 1)];
        int j = 0;
        for (; j + 8 <= m; j += 8) {
            int i0 = __shfl(idx, j + 0 + half);
            int i1 = __shfl(idx, j + 2 + half);
            int i2 = __shfl(idx, j + 4 + half);
            int i3 = __shfl(idx, j + 6 + half);
            float2 a;
            a = unpack_bf16(Gu[(size_t)i0 * 32 + hl]); s0.x += a.x; s0.y += a.y;
            a = unpack_bf16(Gu[(size_t)i1 * 32 + hl]); s1.x += a.x; s1.y += a.y;
            a = unpack_bf16(Gu[(size_t)i2 * 32 + hl]); s2.x += a.x; s2.y += a.y;
            a = unpack_bf16(Gu[(size_t)i3 * 32 + hl]); s3.x += a.x; s3.y += a.y;
        }
        for (; j < m; j += 2) {
            int rem = m - j;
            int ii = __shfl(idx, j + (rem > 1 ? half : 0));
            if (half == 0 || rem > 1) {
                float2 a = unpack_bf16(Gu[(size_t)ii * 32 + hl]);
                s0.x += a.x; s0.y += a.y;
            }
        }
    }
    s0.x += s1.x + s2.x + s3.x;
    s0.y += s1.y + s2.y + s3.y;
    s0.x += __shfl_xor(s0.x, 32);
    s0.y += __shfl_xor(s0.y, 32);
    float2 a = unpack_bf16(Gu[(size_t)wid * 32 + hl]);   // self
    s0.x += a.x; s0.y += a.y;
    float d = dis[wid];
    float2 bb = ((const float2*)b2)[hl];
    if (half == 0) {
        float2 o;
        o.x = fmaf(s0.x, d, bb.x);
        o.y = fmaf(s0.y, d, bb.y);
        ((float2*)out)[(size_t)wid * 32 + hl] = o;
    }
}

// ---------------- launch ----------------

extern "C" void kernel_launch(void* const* d_in, const int* in_sizes, int n_in,
                              void* d_out, int out_size, void* d_ws, size_t ws_size,
                              hipStream_t stream) {
    const float* x  = (const float*)d_in[0];
    const int*   ei = (const int*)d_in[1];
    const float* W1 = (const float*)d_in[2];
    const float* b1 = (const float*)d_in[3];
    const float* W2 = (const float*)d_in[4];
    const float* b2 = (const float*)d_in[5];
    float* out = (float*)d_out;

    int n = in_sizes[0] / IN_CH;       // 100000
    int E = in_sizes[1] / 2;           // 1600000
    const int* srcv = ei;
    const int* dstv = ei + E;

    int NB    = (E + EPB - 1) / EPB;   // 391 edge-blocks
    int NBUCK = (n + 255) >> 8;        // 391 buckets (256 nodes each)
    int L     = NBUCK * NB;            // flat (bucket,block) matrix

    char* w = (char*)d_ws;
    unsigned short* g1 = (unsigned short*)w;  w += (size_t)n * HID * 2;   // 25.6 MB
    unsigned short* h1 = (unsigned short*)w;  w += (size_t)n * HID * 2;   // 25.6 MB
    unsigned short* g2 = g1;                                              // overlay
    unsigned short* wt1 = (unsigned short*)w; w += (size_t)IN_CH * HID * 2;
    unsigned short* wt2 = (unsigned short*)w; w += (size_t)HID * OUT_CH * 2;
    unsigned short* lrank = (unsigned short*)w; w += (size_t)E * 2;       // 3.2 MB
    int*      blockhist = (int*)w; w += (size_t)L * 4;                    // 0.6 MB
    int*      flatscan  = (int*)w; w += (size_t)(L + 1) * 4;
    int*      partial   = (int*)w; w += (size_t)1024 * 4;
    unsigned* sorted    = (unsigned*)w; w += (size_t)E * 4;               // 6.4 MB
    int*      csr       = (int*)w; w += (size_t)E * 4;                    // 6.4 MB
    int*      row_ptr   = (int*)w; w += (size_t)(n + 1) * 4;
    float*    dis       = (float*)w; w += (size_t)n * 4;

    int nb2 = (L + 255) / 256;

    bucket_hist<<<NB, 256, 0, stream>>>(dstv, lrank, blockhist, E, NB, NBUCK);
    scan_partial_kernel<<<nb2, 256, 0, stream>>>(blockhist, partial, L);
    scan_top_kernel<<<1, 1024, 0, stream>>>(partial, nb2, flatscan, L);
    scan_final_kernel<<<nb2, 256, 0, stream>>>(blockhist, partial, flatscan, L);
    bucket_scatter<<<NB, 256, 0, stream>>>(srcv, dstv, lrank, flatscan, sorted, E, NB);
    bucket_finalize<<<NBUCK, 256, 0, stream>>>(sorted, flatscan, csr, row_ptr, dis, NB, n);

    wt_kernel<<<(IN_CH * HID + 255) / 256, 256, 0, stream>>>(W1, wt1, IN_CH, HID);
    wt_kernel<<<(HID * OUT_CH + 255) / 256, 256, 0, stream>>>(W2, wt2, HID, OUT_CH);

    gemm1_mfma<<<(n + 127) / 128, 512, 0, stream>>>(x, wt1, dis, g1, n);
    agg1_kernel<<<(n + 3) / 4, 256, 0, stream>>>((const unsigned*)g1, row_ptr, csr, dis, b1, (unsigned*)h1, n);
    gemm2_mfma<<<(n + 255) / 256, 512, 0, stream>>>(h1, wt2, dis, g2, n);
    agg2_kernel<<<(n + 3) / 4, 256, 0, stream>>>(g2, row_ptr, csr, dis, b2, out, n);
}

// Round 8
// 220.345 us; speedup vs baseline: 3.1066x; 1.0089x over previous
//
#include <hip/hip_runtime.h>

// ---------------------------------------------------------------------------
// GCN 2-layer forward on MI355X.
//  out = Ahat( relu( Ahat (X W1) + b1 ) W2 ) + b2,  Ahat = D^-1/2 (A+I) D^-1/2
// Factored: g = dis .* (X W);  s[i] = g[i] + sum_{e: dst=i} g[src[e]];
//           layer_out[i] = dis[i]*s[i] + b
// R8: GEMMs get register-prefetch pipelining (issue loads 2 steps ahead,
//     ds_write 1 step ahead -> HBM latency hidden under MFMA+ds_read);
//     gemm1 tile 256x128. agg gathers use 32-bit byte offsets (cheap addr).
// ---------------------------------------------------------------------------

constexpr int IN_CH  = 256;
constexpr int HID    = 128;
constexpr int OUT_CH = 64;
constexpr int EPB = 4096;         // edges per block in hist/scatter

typedef __attribute__((ext_vector_type(8))) short short8;
typedef __attribute__((ext_vector_type(4))) float f32x4;

union F8 {                       // one MFMA A/B fragment: 8 bf16
    short8 v;
    unsigned short u[8];
    uint4  q;
};

// ---- bf16 helpers (RNE) ----
__device__ inline unsigned short f2b(float f) {
    unsigned u = __float_as_uint(f);
    u += 0x7fffu + ((u >> 16) & 1u);
    return (unsigned short)(u >> 16);
}
__device__ inline unsigned pack_bf16(float a, float b) {
    unsigned ua = __float_as_uint(a); ua += 0x7fffu + ((ua >> 16) & 1u);
    unsigned ub = __float_as_uint(b); ub += 0x7fffu + ((ub >> 16) & 1u);
    return (ua >> 16) | (ub & 0xffff0000u);
}
__device__ inline float2 unpack_bf16(unsigned v) {
    return make_float2(__uint_as_float(v << 16), __uint_as_float(v & 0xffff0000u));
}

// ---------------- CSR build (bucket radix, LDS atomics only) ----------------

__global__ __launch_bounds__(256) void bucket_hist(
    const int* __restrict__ dst, unsigned short* __restrict__ lrank,
    int* __restrict__ blockhist, int E, int NB, int NBUCK) {
    __shared__ int lbin[512];
    for (int l = threadIdx.x; l < 512; l += 256) lbin[l] = 0;
    __syncthreads();
    int base = blockIdx.x * EPB;
    #pragma unroll 4
    for (int j = 0; j < EPB / 256; ++j) {
        int e = base + j * 256 + threadIdx.x;
        if (e < E) {
            int b = ((unsigned)dst[e]) >> 8;
            lrank[e] = (unsigned short)atomicAdd(&lbin[b], 1);
        }
    }
    __syncthreads();
    for (int l = threadIdx.x; l < NBUCK; l += 256)
        blockhist[l * NB + blockIdx.x] = lbin[l];   // bucket-major
}

__global__ void scan_partial_kernel(const int* __restrict__ in, int* __restrict__ partial, int len) {
    __shared__ int sh[256];
    int i = blockIdx.x * 256 + threadIdx.x;
    int v = (i < len) ? in[i] : 0;
    sh[threadIdx.x] = v;
    __syncthreads();
    for (int ofs = 128; ofs > 0; ofs >>= 1) {
        if (threadIdx.x < ofs) sh[threadIdx.x] += sh[threadIdx.x + ofs];
        __syncthreads();
    }
    if (threadIdx.x == 0) partial[blockIdx.x] = sh[0];
}

__global__ __launch_bounds__(1024) void scan_top_kernel(
    int* __restrict__ partial, int nb, int* __restrict__ out, int L) {
    __shared__ int sh[1024];
    int t = threadIdx.x;
    int v = (t < nb) ? partial[t] : 0;
    sh[t] = v;
    __syncthreads();
    for (int ofs = 1; ofs < 1024; ofs <<= 1) {
        int tv = (t >= ofs) ? sh[t - ofs] : 0;
        __syncthreads();
        sh[t] += tv;
        __syncthreads();
    }
    if (t < nb) partial[t] = sh[t] - v;          // exclusive
    if (t == 1023) out[L] = sh[1023];            // grand total (== E)
}

__global__ void scan_final_kernel(const int* __restrict__ in, const int* __restrict__ partial,
                                  int* __restrict__ out, int len) {
    __shared__ int sh[256];
    int i = blockIdx.x * 256 + threadIdx.x;
    int v = (i < len) ? in[i] : 0;
    sh[threadIdx.x] = v;
    __syncthreads();
    for (int ofs = 1; ofs < 256; ofs <<= 1) {
        int t = 0;
        if (threadIdx.x >= ofs) t = sh[threadIdx.x - ofs];
        __syncthreads();
        if (threadIdx.x >= ofs) sh[threadIdx.x] += t;
        __syncthreads();
    }
    if (i < len) out[i] = partial[blockIdx.x] + sh[threadIdx.x] - v;   // exclusive
}

__global__ __launch_bounds__(256) void bucket_scatter(
    const int* __restrict__ src, const int* __restrict__ dst,
    const unsigned short* __restrict__ lrank, const int* __restrict__ flatscan,
    unsigned* __restrict__ sorted, int E, int NB) {
    int base = blockIdx.x * EPB;
    #pragma unroll 4
    for (int j = 0; j < EPB / 256; ++j) {
        int e = base + j * 256 + threadIdx.x;
        if (e < E) {
            int d = dst[e];
            int b = ((unsigned)d) >> 8;
            int slot = flatscan[b * NB + blockIdx.x] + (int)lrank[e];
            sorted[slot] = (((unsigned)(d & 255)) << 24) | (unsigned)src[e];
        }
    }
}

__global__ __launch_bounds__(256) void bucket_finalize(
    const unsigned* __restrict__ sorted, const int* __restrict__ flatscan,
    int* __restrict__ csr_src, int* __restrict__ row_ptr, float* __restrict__ dis,
    int NB, int n) {
    __shared__ int cnt[256];
    __shared__ int sh[256];
    __shared__ int cur[256];
    int b = blockIdx.x;
    int t = threadIdx.x;
    int ebeg = flatscan[b * NB];
    int eend = flatscan[(b + 1) * NB];
    cnt[t] = 0;
    __syncthreads();
    for (int e = ebeg + t; e < eend; e += 256)
        atomicAdd(&cnt[sorted[e] >> 24], 1);
    __syncthreads();
    int v = cnt[t];
    sh[t] = v;
    __syncthreads();
    for (int ofs = 1; ofs < 256; ofs <<= 1) {
        int tv = (t >= ofs) ? sh[t - ofs] : 0;
        __syncthreads();
        sh[t] += tv;
        __syncthreads();
    }
    int excl = sh[t] - v;
    int node = b * 256 + t;
    if (node <= n) row_ptr[node] = ebeg + excl;
    if (node < n)  dis[node] = rsqrtf(1.0f + (float)v);
    cur[t] = excl;
    __syncthreads();
    for (int e = ebeg + t; e < eend; e += 256) {
        unsigned s = sorted[e];
        int pos = atomicAdd(&cur[s >> 24], 1);
        csr_src[ebeg + pos] = (int)(s & 0xFFFFFFu);
    }
}

// ---------------- W transpose + bf16: Wt[c][k] = bf16(W[k][c]) ---------------

__global__ void wt_kernel(const float* __restrict__ W, unsigned short* __restrict__ Wt,
                          int K, int N) {
    int idx = blockIdx.x * 256 + threadIdx.x;    // idx = c*K + k
    if (idx >= K * N) return;
    int c = idx / K, k = idx - c * K;
    Wt[idx] = f2b(W[(size_t)k * N + c]);
}

// ---------------- GEMM 1 (MFMA + LDS + reg prefetch) -------------------------
// Tile 256x128, 8 waves (4M x 2N), wave tile 64x64, BK=32, 8 K-steps.
// Pipeline: step ks does { ds_write slab ks+1 (regs), issue load slab ks+2,
// ds_read frags of slab ks, 16 MFMA, barrier }.

__global__ __launch_bounds__(512) void gemm1_mfma(
    const float* __restrict__ X, const unsigned short* __restrict__ Wt,
    const float* __restrict__ dis, unsigned short* __restrict__ G, int n) {
    constexpr int K = 256, LP = 20, NS = 8;
    __shared__ unsigned xs[2][256 * LP];          // 2 x 20KB

    int tid  = threadIdx.x;
    int lane = tid & 63;
    int w    = tid >> 6;
    int wm = w >> 1, wn = w & 1;
    int rowbase = blockIdx.x * 256 + wm * 64;
    int colbase = wn * 64;
    int la = lane & 15, lb = lane >> 4;

    // staging: thread -> (row, half): 16 consecutive f32 each
    int srow = tid >> 1, shalf = tid & 1;
    int grow = blockIdx.x * 256 + srow;
    if (grow >= n) grow = n - 1;
    const float* xrow = X + (size_t)grow * K + shalf * 16;
    int sofs = srow * LP + shalf * 8;             // uint offset in xs

    float4 pf0, pf1, pf2, pf3;
    #define G1_LOAD(ks) { const float* p_ = xrow + (ks) * 32;                 \
        pf0 = *(const float4*)(p_);     pf1 = *(const float4*)(p_ + 4);       \
        pf2 = *(const float4*)(p_ + 8); pf3 = *(const float4*)(p_ + 12); }
    #define G1_WRITE(buf) { uint4 o_;                                         \
        o_.x = pack_bf16(pf0.x, pf0.y); o_.y = pack_bf16(pf0.z, pf0.w);       \
        o_.z = pack_bf16(pf1.x, pf1.y); o_.w = pack_bf16(pf1.z, pf1.w);       \
        *(uint4*)&xs[buf][sofs] = o_;                                         \
        o_.x = pack_bf16(pf2.x, pf2.y); o_.y = pack_bf16(pf2.z, pf2.w);       \
        o_.z = pack_bf16(pf3.x, pf3.y); o_.w = pack_bf16(pf3.z, pf3.w);       \
        *(uint4*)&xs[buf][sofs + 4] = o_; }

    f32x4 acc[4][4];
    #pragma unroll
    for (int m = 0; m < 4; ++m)
        #pragma unroll
        for (int nn = 0; nn < 4; ++nn) acc[m][nn] = (f32x4){0.f, 0.f, 0.f, 0.f};

    G1_LOAD(0);
    G1_WRITE(0);
    G1_LOAD(1);
    __syncthreads();

    #pragma unroll
    for (int ks = 0; ks < NS; ++ks) {
        int cur = ks & 1;
        if (ks + 1 < NS) G1_WRITE(cur ^ 1);       // regs hold slab ks+1
        if (ks + 2 < NS) G1_LOAD(ks + 2);         // issue early, consume next step
        F8 a[4], b[4];
        #pragma unroll
        for (int m = 0; m < 4; ++m)
            a[m].q = *(const uint4*)&xs[cur][(wm * 64 + m * 16 + la) * LP + lb * 4];
        #pragma unroll
        for (int nn = 0; nn < 4; ++nn) {
            int col = colbase + nn * 16 + la;
            b[nn].q = *(const uint4*)(Wt + (size_t)col * K + ks * 32 + lb * 8);
        }
        #pragma unroll
        for (int m = 0; m < 4; ++m)
            #pragma unroll
            for (int nn = 0; nn < 4; ++nn)
                acc[m][nn] = __builtin_amdgcn_mfma_f32_16x16x32_bf16(
                    a[m].v, b[nn].v, acc[m][nn], 0, 0, 0);
        __syncthreads();
    }
    #undef G1_LOAD
    #undef G1_WRITE

    #pragma unroll
    for (int m = 0; m < 4; ++m) {
        int r0 = rowbase + m * 16 + lb * 4;
        float dv[4];
        #pragma unroll
        for (int r = 0; r < 4; ++r) dv[r] = (r0 + r < n) ? dis[r0 + r] : 0.f;
        #pragma unroll
        for (int nn = 0; nn < 4; ++nn) {
            int col = colbase + nn * 16 + la;
            #pragma unroll
            for (int r = 0; r < 4; ++r) {
                int row = r0 + r;
                if (row < n)
                    G[(size_t)row * HID + col] = f2b(acc[m][nn][r] * dv[r]);
            }
        }
    }
}

// ---------------- GEMM 2 (MFMA + LDS + reg prefetch) -------------------------
// Tile 256x64, 8 waves (4M x 2N), wave tile 64x32, BK=32, 4 K-steps.

__global__ __launch_bounds__(512) void gemm2_mfma(
    const unsigned short* __restrict__ H, const unsigned short* __restrict__ Wt,
    const float* __restrict__ dis, unsigned short* __restrict__ G, int n) {
    constexpr int K = 128, LP = 20, NS = 4;
    __shared__ unsigned xs[2][256 * LP];

    int tid  = threadIdx.x;
    int lane = tid & 63;
    int w    = tid >> 6;
    int wm = w >> 1, wn = w & 1;
    int rowbase = blockIdx.x * 256 + wm * 64;
    int colbase = wn * 32;
    int la = lane & 15, lb = lane >> 4;

    const unsigned* Hu = (const unsigned*)H;      // 64 uints per row

    int sr0 = tid >> 2, sq0 = tid & 3;
    int sr1 = (tid + 512) >> 2, sq1 = tid & 3;
    int g0 = blockIdx.x * 256 + sr0; g0 = g0 < n ? g0 : n - 1;
    int g1 = blockIdx.x * 256 + sr1; g1 = g1 < n ? g1 : n - 1;

    uint4 pf0, pf1;
    #define G2_LOAD(ks) {                                                     \
        pf0 = *(const uint4*)&Hu[(size_t)g0 * 64 + (ks) * 16 + sq0 * 4];      \
        pf1 = *(const uint4*)&Hu[(size_t)g1 * 64 + (ks) * 16 + sq1 * 4]; }
    #define G2_WRITE(buf) {                                                   \
        *(uint4*)&xs[buf][sr0 * LP + sq0 * 4] = pf0;                          \
        *(uint4*)&xs[buf][sr1 * LP + sq1 * 4] = pf1; }

    f32x4 acc[4][2];
    #pragma unroll
    for (int m = 0; m < 4; ++m)
        #pragma unroll
        for (int nn = 0; nn < 2; ++nn) acc[m][nn] = (f32x4){0.f, 0.f, 0.f, 0.f};

    G2_LOAD(0);
    G2_WRITE(0);
    G2_LOAD(1);
    __syncthreads();

    #pragma unroll
    for (int ks = 0; ks < NS; ++ks) {
        int cur = ks & 1;
        if (ks + 1 < NS) G2_WRITE(cur ^ 1);
        if (ks + 2 < NS) G2_LOAD(ks + 2);
        F8 a[4], b[2];
        #pragma unroll
        for (int m = 0; m < 4; ++m)
            a[m].q = *(const uint4*)&xs[cur][(wm * 64 + m * 16 + la) * LP + lb * 4];
        #pragma unroll
        for (int nn = 0; nn < 2; ++nn) {
            int col = colbase + nn * 16 + la;
            b[nn].q = *(const uint4*)(Wt + (size_t)col * K + ks * 32 + lb * 8);
        }
        #pragma unroll
        for (int m = 0; m < 4; ++m)
            #pragma unroll
            for (int nn = 0; nn < 2; ++nn)
                acc[m][nn] = __builtin_amdgcn_mfma_f32_16x16x32_bf16(
                    a[m].v, b[nn].v, acc[m][nn], 0, 0, 0);
        __syncthreads();
    }
    #undef G2_LOAD
    #undef G2_WRITE

    #pragma unroll
    for (int m = 0; m < 4; ++m) {
        int r0 = rowbase + m * 16 + lb * 4;
        float dv[4];
        #pragma unroll
        for (int r = 0; r < 4; ++r) dv[r] = (r0 + r < n) ? dis[r0 + r] : 0.f;
        #pragma unroll
        for (int nn = 0; nn < 2; ++nn) {
            int col = colbase + nn * 16 + la;
            #pragma unroll
            for (int r = 0; r < 4; ++r) {
                int row = r0 + r;
                if (row < n)
                    G[(size_t)row * OUT_CH + col] = f2b(acc[m][nn][r] * dv[r]);
            }
        }
    }
}

// ---------------- Aggregation 1: h1 = bf16(relu(dis .* (self+gather) + b1)) --
// Half-wave per edge, 8 gathers in flight, 32-bit byte-offset addressing.

__global__ __launch_bounds__(256) void agg1_kernel(
    const unsigned* __restrict__ G, const int* __restrict__ row_ptr,
    const int* __restrict__ csr_src, const float* __restrict__ dis,
    const float* __restrict__ b1, unsigned* __restrict__ H, int n) {
    int wid = (blockIdx.x * blockDim.x + threadIdx.x) >> 6;
    int lane = threadIdx.x & 63;
    if (wid >= n) return;
    int half = lane >> 5, hl = lane & 31;
    const char* Gb = (const char*)G;              // row = 256B
    unsigned lofs = (unsigned)(hl << 3);
    float4 s0 = {0,0,0,0}, s1 = {0,0,0,0}, s2 = {0,0,0,0}, s3 = {0,0,0,0};
    int beg = row_ptr[wid], end = row_ptr[wid + 1];
    for (int base = beg; base < end; base += 64) {
        int m = end - base; if (m > 64) m = 64;
        int idx = csr_src[base + (lane < m ? lane : m - 1)];
        int j = 0;
        for (; j + 8 <= m; j += 8) {
            unsigned o0 = ((unsigned)__shfl(idx, j + 0 + half) << 8) + lofs;
            unsigned o1 = ((unsigned)__shfl(idx, j + 2 + half) << 8) + lofs;
            unsigned o2 = ((unsigned)__shfl(idx, j + 4 + half) << 8) + lofs;
            unsigned o3 = ((unsigned)__shfl(idx, j + 6 + half) << 8) + lofs;
            uint2 u0 = *(const uint2*)(Gb + o0);
            uint2 u1 = *(const uint2*)(Gb + o1);
            uint2 u2 = *(const uint2*)(Gb + o2);
            uint2 u3 = *(const uint2*)(Gb + o3);
            float2 a, b;
            a = unpack_bf16(u0.x); b = unpack_bf16(u0.y);
            s0.x += a.x; s0.y += a.y; s0.z += b.x; s0.w += b.y;
            a = unpack_bf16(u1.x); b = unpack_bf16(u1.y);
            s1.x += a.x; s1.y += a.y; s1.z += b.x; s1.w += b.y;
            a = unpack_bf16(u2.x); b = unpack_bf16(u2.y);
            s2.x += a.x; s2.y += a.y; s2.z += b.x; s2.w += b.y;
            a = unpack_bf16(u3.x); b = unpack_bf16(u3.y);
            s3.x += a.x; s3.y += a.y; s3.z += b.x; s3.w += b.y;
        }
        for (; j < m; j += 2) {
            int rem = m - j;
            int ii = __shfl(idx, j + (rem > 1 ? half : 0));
            if (half == 0 || rem > 1) {
                uint2 u = *(const uint2*)(Gb + (((unsigned)ii << 8) + lofs));
                float2 a = unpack_bf16(u.x), b = unpack_bf16(u.y);
                s0.x += a.x; s0.y += a.y; s0.z += b.x; s0.w += b.y;
            }
        }
    }
    s0.x += s1.x + s2.x + s3.x;
    s0.y += s1.y + s2.y + s3.y;
    s0.z += s1.z + s2.z + s3.z;
    s0.w += s1.w + s2.w + s3.w;
    s0.x += __shfl_xor(s0.x, 32);
    s0.y += __shfl_xor(s0.y, 32);
    s0.z += __shfl_xor(s0.z, 32);
    s0.w += __shfl_xor(s0.w, 32);
    uint2 su = *(const uint2*)(Gb + (((unsigned)wid << 8) + lofs));   // self
    float2 a = unpack_bf16(su.x), b = unpack_bf16(su.y);
    s0.x += a.x; s0.y += a.y; s0.z += b.x; s0.w += b.y;
    float d = dis[wid];
    float4 bb = ((const float4*)b1)[hl];
    float o0 = fmaxf(fmaf(s0.x, d, bb.x), 0.f);
    float o1 = fmaxf(fmaf(s0.y, d, bb.y), 0.f);
    float o2 = fmaxf(fmaf(s0.z, d, bb.z), 0.f);
    float o3 = fmaxf(fmaf(s0.w, d, bb.w), 0.f);
    if (half == 0) {
        uint2 ou;
        ou.x = pack_bf16(o0, o1);
        ou.y = pack_bf16(o2, o3);
        ((uint2*)H)[(size_t)wid * 32 + hl] = ou;
    }
}

// ---------------- Aggregation 2: out = dis .* (self+gather) + b2 -------------

__global__ __launch_bounds__(256) void agg2_kernel(
    const unsigned short* __restrict__ G, const int* __restrict__ row_ptr,
    const int* __restrict__ csr_src, const float* __restrict__ dis,
    const float* __restrict__ b2, float* __restrict__ out, int n) {
    int wid = (blockIdx.x * blockDim.x + threadIdx.x) >> 6;
    int lane = threadIdx.x & 63;
    if (wid >= n) return;
    int half = lane >> 5, hl = lane & 31;
    const char* Gb = (const char*)G;              // row = 128B
    unsigned lofs = (unsigned)(hl << 2);
    float2 s0 = {0,0}, s1 = {0,0}, s2 = {0,0}, s3 = {0,0};
    int beg = row_ptr[wid], end = row_ptr[wid + 1];
    for (int base = beg; base < end; base += 64) {
        int m = end - base; if (m > 64) m = 64;
        int idx = csr_src[base + (lane < m ? lane : m - 1)];
        int j = 0;
        for (; j + 8 <= m; j += 8) {
            unsigned o0 = ((unsigned)__shfl(idx, j + 0 + half) << 7) + lofs;
            unsigned o1 = ((unsigned)__shfl(idx, j + 2 + half) << 7) + lofs;
            unsigned o2 = ((unsigned)__shfl(idx, j + 4 + half) << 7) + lofs;
            unsigned o3 = ((unsigned)__shfl(idx, j + 6 + half) << 7) + lofs;
            float2 a;
            a = unpack_bf16(*(const unsigned*)(Gb + o0)); s0.x += a.x; s0.y += a.y;
            a = unpack_bf16(*(const unsigned*)(Gb + o1)); s1.x += a.x; s1.y += a.y;
            a = unpack_bf16(*(const unsigned*)(Gb + o2)); s2.x += a.x; s2.y += a.y;
            a = unpack_bf16(*(const unsigned*)(Gb + o3)); s3.x += a.x; s3.y += a.y;
        }
        for (; j < m; j += 2) {
            int rem = m - j;
            int ii = __shfl(idx, j + (rem > 1 ? half : 0));
            if (half == 0 || rem > 1) {
                float2 a = unpack_bf16(*(const unsigned*)(Gb + (((unsigned)ii << 7) + lofs)));
                s0.x += a.x; s0.y += a.y;
            }
        }
    }
    s0.x += s1.x + s2.x + s3.x;
    s0.y += s1.y + s2.y + s3.y;
    s0.x += __shfl_xor(s0.x, 32);
    s0.y += __shfl_xor(s0.y, 32);
    float2 a = unpack_bf16(*(const unsigned*)(Gb + (((unsigned)wid << 7) + lofs)));
    s0.x += a.x; s0.y += a.y;
    float d = dis[wid];
    float2 bb = ((const float2*)b2)[hl];
    if (half == 0) {
        float2 o;
        o.x = fmaf(s0.x, d, bb.x);
        o.y = fmaf(s0.y, d, bb.y);
        ((float2*)out)[(size_t)wid * 32 + hl] = o;
    }
}

// ---------------- launch ----------------

extern "C" void kernel_launch(void* const* d_in, const int* in_sizes, int n_in,
                              void* d_out, int out_size, void* d_ws, size_t ws_size,
                              hipStream_t stream) {
    const float* x  = (const float*)d_in[0];
    const int*   ei = (const int*)d_in[1];
    const float* W1 = (const float*)d_in[2];
    const float* b1 = (const float*)d_in[3];
    const float* W2 = (const float*)d_in[4];
    const float* b2 = (const float*)d_in[5];
    float* out = (float*)d_out;

    int n = in_sizes[0] / IN_CH;       // 100000
    int E = in_sizes[1] / 2;           // 1600000
    const int* srcv = ei;
    const int* dstv = ei + E;

    int NB    = (E + EPB - 1) / EPB;   // 391 edge-blocks
    int NBUCK = (n + 255) >> 8;        // 391 buckets (256 nodes each)
    int L     = NBUCK * NB;

    char* w = (char*)d_ws;
    unsigned short* g1 = (unsigned short*)w;  w += (size_t)n * HID * 2;   // 25.6 MB
    unsigned short* h1 = (unsigned short*)w;  w += (size_t)n * HID * 2;   // 25.6 MB
    unsigned short* g2 = g1;                                              // overlay
    unsigned short* wt1 = (unsigned short*)w; w += (size_t)IN_CH * HID * 2;
    unsigned short* wt2 = (unsigned short*)w; w += (size_t)HID * OUT_CH * 2;
    unsigned short* lrank = (unsigned short*)w; w += (size_t)E * 2;       // 3.2 MB
    int*      blockhist = (int*)w; w += (size_t)L * 4;
    int*      flatscan  = (int*)w; w += (size_t)(L + 1) * 4;
    int*      partial   = (int*)w; w += (size_t)1024 * 4;
    unsigned* sorted    = (unsigned*)w; w += (size_t)E * 4;               // 6.4 MB
    int*      csr       = (int*)w; w += (size_t)E * 4;                    // 6.4 MB
    int*      row_ptr   = (int*)w; w += (size_t)(n + 1) * 4;
    float*    dis       = (float*)w; w += (size_t)n * 4;

    int nb2 = (L + 255) / 256;

    bucket_hist<<<NB, 256, 0, stream>>>(dstv, lrank, blockhist, E, NB, NBUCK);
    scan_partial_kernel<<<nb2, 256, 0, stream>>>(blockhist, partial, L);
    scan_top_kernel<<<1, 1024, 0, stream>>>(partial, nb2, flatscan, L);
    scan_final_kernel<<<nb2, 256, 0, stream>>>(blockhist, partial, flatscan, L);
    bucket_scatter<<<NB, 256, 0, stream>>>(srcv, dstv, lrank, flatscan, sorted, E, NB);
    bucket_finalize<<<NBUCK, 256, 0, stream>>>(sorted, flatscan, csr, row_ptr, dis, NB, n);

    wt_kernel<<<(IN_CH * HID + 255) / 256, 256, 0, stream>>>(W1, wt1, IN_CH, HID);
    wt_kernel<<<(HID * OUT_CH + 255) / 256, 256, 0, stream>>>(W2, wt2, HID, OUT_CH);

    gemm1_mfma<<<(n + 255) / 256, 512, 0, stream>>>(x, wt1, dis, g1, n);
    agg1_kernel<<<(n + 3) / 4, 256, 0, stream>>>((const unsigned*)g1, row_ptr, csr, dis, b1, (unsigned*)h1, n);
    gemm2_mfma<<<(n + 255) / 256, 512, 0, stream>>>(h1, wt2, dis, g2, n);
    agg2_kernel<<<(n + 3) / 4, 256, 0, stream>>>(g2, row_ptr, csr, dis, b2, out, n);
}

// Round 9
// 218.834 us; speedup vs baseline: 3.1281x; 1.0069x over previous
//
#include <hip/hip_runtime.h>

// ---------------------------------------------------------------------------
// GCN 2-layer forward on MI355X.
//  out = Ahat( relu( Ahat (X W1) + b1 ) W2 ) + b2,  Ahat = D^-1/2 (A+I) D^-1/2
// Factored: g = dis .* (X W);  s[i] = g[i] + sum_{e: dst=i} g[src[e]];
//           layer_out[i] = dis[i]*s[i] + b
// R9: agg kernels quarter-wave (16 lanes/edge, uint4/uint2 per lane):
//     4 edges per wave-step, 16 gathers (4KB) in flight, ~half the VALU.
// ---------------------------------------------------------------------------

constexpr int IN_CH  = 256;
constexpr int HID    = 128;
constexpr int OUT_CH = 64;
constexpr int EPB = 4096;         // edges per block in hist/scatter

typedef __attribute__((ext_vector_type(8))) short short8;
typedef __attribute__((ext_vector_type(4))) float f32x4;

union F8 {                       // one MFMA A/B fragment: 8 bf16
    short8 v;
    unsigned short u[8];
    uint4  q;
};

// ---- bf16 helpers (RNE) ----
__device__ inline unsigned short f2b(float f) {
    unsigned u = __float_as_uint(f);
    u += 0x7fffu + ((u >> 16) & 1u);
    return (unsigned short)(u >> 16);
}
__device__ inline unsigned pack_bf16(float a, float b) {
    unsigned ua = __float_as_uint(a); ua += 0x7fffu + ((ua >> 16) & 1u);
    unsigned ub = __float_as_uint(b); ub += 0x7fffu + ((ub >> 16) & 1u);
    return (ua >> 16) | (ub & 0xffff0000u);
}
__device__ inline float2 unpack_bf16(unsigned v) {
    return make_float2(__uint_as_float(v << 16), __uint_as_float(v & 0xffff0000u));
}

// ---------------- CSR build (bucket radix, LDS atomics only) ----------------

__global__ __launch_bounds__(256) void bucket_hist(
    const int* __restrict__ dst, unsigned short* __restrict__ lrank,
    int* __restrict__ blockhist, int E, int NB, int NBUCK) {
    __shared__ int lbin[512];
    for (int l = threadIdx.x; l < 512; l += 256) lbin[l] = 0;
    __syncthreads();
    int base = blockIdx.x * EPB;
    #pragma unroll 4
    for (int j = 0; j < EPB / 256; ++j) {
        int e = base + j * 256 + threadIdx.x;
        if (e < E) {
            int b = ((unsigned)dst[e]) >> 8;
            lrank[e] = (unsigned short)atomicAdd(&lbin[b], 1);
        }
    }
    __syncthreads();
    for (int l = threadIdx.x; l < NBUCK; l += 256)
        blockhist[l * NB + blockIdx.x] = lbin[l];   // bucket-major
}

__global__ void scan_partial_kernel(const int* __restrict__ in, int* __restrict__ partial, int len) {
    __shared__ int sh[256];
    int i = blockIdx.x * 256 + threadIdx.x;
    int v = (i < len) ? in[i] : 0;
    sh[threadIdx.x] = v;
    __syncthreads();
    for (int ofs = 128; ofs > 0; ofs >>= 1) {
        if (threadIdx.x < ofs) sh[threadIdx.x] += sh[threadIdx.x + ofs];
        __syncthreads();
    }
    if (threadIdx.x == 0) partial[blockIdx.x] = sh[0];
}

__global__ __launch_bounds__(1024) void scan_top_kernel(
    int* __restrict__ partial, int nb, int* __restrict__ out, int L) {
    __shared__ int sh[1024];
    int t = threadIdx.x;
    int v = (t < nb) ? partial[t] : 0;
    sh[t] = v;
    __syncthreads();
    for (int ofs = 1; ofs < 1024; ofs <<= 1) {
        int tv = (t >= ofs) ? sh[t - ofs] : 0;
        __syncthreads();
        sh[t] += tv;
        __syncthreads();
    }
    if (t < nb) partial[t] = sh[t] - v;          // exclusive
    if (t == 1023) out[L] = sh[1023];            // grand total (== E)
}

__global__ void scan_final_kernel(const int* __restrict__ in, const int* __restrict__ partial,
                                  int* __restrict__ out, int len) {
    __shared__ int sh[256];
    int i = blockIdx.x * 256 + threadIdx.x;
    int v = (i < len) ? in[i] : 0;
    sh[threadIdx.x] = v;
    __syncthreads();
    for (int ofs = 1; ofs < 256; ofs <<= 1) {
        int t = 0;
        if (threadIdx.x >= ofs) t = sh[threadIdx.x - ofs];
        __syncthreads();
        if (threadIdx.x >= ofs) sh[threadIdx.x] += t;
        __syncthreads();
    }
    if (i < len) out[i] = partial[blockIdx.x] + sh[threadIdx.x] - v;   // exclusive
}

__global__ __launch_bounds__(256) void bucket_scatter(
    const int* __restrict__ src, const int* __restrict__ dst,
    const unsigned short* __restrict__ lrank, const int* __restrict__ flatscan,
    unsigned* __restrict__ sorted, int E, int NB) {
    int base = blockIdx.x * EPB;
    #pragma unroll 4
    for (int j = 0; j < EPB / 256; ++j) {
        int e = base + j * 256 + threadIdx.x;
        if (e < E) {
            int d = dst[e];
            int b = ((unsigned)d) >> 8;
            int slot = flatscan[b * NB + blockIdx.x] + (int)lrank[e];
            sorted[slot] = (((unsigned)(d & 255)) << 24) | (unsigned)src[e];
        }
    }
}

__global__ __launch_bounds__(256) void bucket_finalize(
    const unsigned* __restrict__ sorted, const int* __restrict__ flatscan,
    int* __restrict__ csr_src, int* __restrict__ row_ptr, float* __restrict__ dis,
    int NB, int n) {
    __shared__ int cnt[256];
    __shared__ int sh[256];
    __shared__ int cur[256];
    int b = blockIdx.x;
    int t = threadIdx.x;
    int ebeg = flatscan[b * NB];
    int eend = flatscan[(b + 1) * NB];
    cnt[t] = 0;
    __syncthreads();
    for (int e = ebeg + t; e < eend; e += 256)
        atomicAdd(&cnt[sorted[e] >> 24], 1);
    __syncthreads();
    int v = cnt[t];
    sh[t] = v;
    __syncthreads();
    for (int ofs = 1; ofs < 256; ofs <<= 1) {
        int tv = (t >= ofs) ? sh[t - ofs] : 0;
        __syncthreads();
        sh[t] += tv;
        __syncthreads();
    }
    int excl = sh[t] - v;
    int node = b * 256 + t;
    if (node <= n) row_ptr[node] = ebeg + excl;
    if (node < n)  dis[node] = rsqrtf(1.0f + (float)v);
    cur[t] = excl;
    __syncthreads();
    for (int e = ebeg + t; e < eend; e += 256) {
        unsigned s = sorted[e];
        int pos = atomicAdd(&cur[s >> 24], 1);
        csr_src[ebeg + pos] = (int)(s & 0xFFFFFFu);
    }
}

// ---------------- W transpose + bf16: Wt[c][k] = bf16(W[k][c]) ---------------

__global__ void wt_kernel(const float* __restrict__ W, unsigned short* __restrict__ Wt,
                          int K, int N) {
    int idx = blockIdx.x * 256 + threadIdx.x;    // idx = c*K + k
    if (idx >= K * N) return;
    int c = idx / K, k = idx - c * K;
    Wt[idx] = f2b(W[(size_t)k * N + c]);
}

// ---------------- GEMM 1 (MFMA + LDS + reg prefetch) -------------------------

__global__ __launch_bounds__(512) void gemm1_mfma(
    const float* __restrict__ X, const unsigned short* __restrict__ Wt,
    const float* __restrict__ dis, unsigned short* __restrict__ G, int n) {
    constexpr int K = 256, LP = 20, NS = 8;
    __shared__ unsigned xs[2][256 * LP];          // 2 x 20KB

    int tid  = threadIdx.x;
    int lane = tid & 63;
    int w    = tid >> 6;
    int wm = w >> 1, wn = w & 1;
    int rowbase = blockIdx.x * 256 + wm * 64;
    int colbase = wn * 64;
    int la = lane & 15, lb = lane >> 4;

    int srow = tid >> 1, shalf = tid & 1;
    int grow = blockIdx.x * 256 + srow;
    if (grow >= n) grow = n - 1;
    const float* xrow = X + (size_t)grow * K + shalf * 16;
    int sofs = srow * LP + shalf * 8;             // uint offset in xs

    float4 pf0, pf1, pf2, pf3;
    #define G1_LOAD(ks) { const float* p_ = xrow + (ks) * 32;                 \
        pf0 = *(const float4*)(p_);     pf1 = *(const float4*)(p_ + 4);       \
        pf2 = *(const float4*)(p_ + 8); pf3 = *(const float4*)(p_ + 12); }
    #define G1_WRITE(buf) { uint4 o_;                                         \
        o_.x = pack_bf16(pf0.x, pf0.y); o_.y = pack_bf16(pf0.z, pf0.w);       \
        o_.z = pack_bf16(pf1.x, pf1.y); o_.w = pack_bf16(pf1.z, pf1.w);       \
        *(uint4*)&xs[buf][sofs] = o_;                                         \
        o_.x = pack_bf16(pf2.x, pf2.y); o_.y = pack_bf16(pf2.z, pf2.w);       \
        o_.z = pack_bf16(pf3.x, pf3.y); o_.w = pack_bf16(pf3.z, pf3.w);       \
        *(uint4*)&xs[buf][sofs + 4] = o_; }

    f32x4 acc[4][4];
    #pragma unroll
    for (int m = 0; m < 4; ++m)
        #pragma unroll
        for (int nn = 0; nn < 4; ++nn) acc[m][nn] = (f32x4){0.f, 0.f, 0.f, 0.f};

    G1_LOAD(0);
    G1_WRITE(0);
    G1_LOAD(1);
    __syncthreads();

    #pragma unroll
    for (int ks = 0; ks < NS; ++ks) {
        int cur = ks & 1;
        if (ks + 1 < NS) G1_WRITE(cur ^ 1);       // regs hold slab ks+1
        if (ks + 2 < NS) G1_LOAD(ks + 2);         // issue early, consume next step
        F8 a[4], b[4];
        #pragma unroll
        for (int m = 0; m < 4; ++m)
            a[m].q = *(const uint4*)&xs[cur][(wm * 64 + m * 16 + la) * LP + lb * 4];
        #pragma unroll
        for (int nn = 0; nn < 4; ++nn) {
            int col = colbase + nn * 16 + la;
            b[nn].q = *(const uint4*)(Wt + (size_t)col * K + ks * 32 + lb * 8);
        }
        #pragma unroll
        for (int m = 0; m < 4; ++m)
            #pragma unroll
            for (int nn = 0; nn < 4; ++nn)
                acc[m][nn] = __builtin_amdgcn_mfma_f32_16x16x32_bf16(
                    a[m].v, b[nn].v, acc[m][nn], 0, 0, 0);
        __syncthreads();
    }
    #undef G1_LOAD
    #undef G1_WRITE

    #pragma unroll
    for (int m = 0; m < 4; ++m) {
        int r0 = rowbase + m * 16 + lb * 4;
        float dv[4];
        #pragma unroll
        for (int r = 0; r < 4; ++r) dv[r] = (r0 + r < n) ? dis[r0 + r] : 0.f;
        #pragma unroll
        for (int nn = 0; nn < 4; ++nn) {
            int col = colbase + nn * 16 + la;
            #pragma unroll
            for (int r = 0; r < 4; ++r) {
                int row = r0 + r;
                if (row < n)
                    G[(size_t)row * HID + col] = f2b(acc[m][nn][r] * dv[r]);
            }
        }
    }
}

// ---------------- GEMM 2 (MFMA + LDS + reg prefetch) -------------------------

__global__ __launch_bounds__(512) void gemm2_mfma(
    const unsigned short* __restrict__ H, const unsigned short* __restrict__ Wt,
    const float* __restrict__ dis, unsigned short* __restrict__ G, int n) {
    constexpr int K = 128, LP = 20, NS = 4;
    __shared__ unsigned xs[2][256 * LP];

    int tid  = threadIdx.x;
    int lane = tid & 63;
    int w    = tid >> 6;
    int wm = w >> 1, wn = w & 1;
    int rowbase = blockIdx.x * 256 + wm * 64;
    int colbase = wn * 32;
    int la = lane & 15, lb = lane >> 4;

    const unsigned* Hu = (const unsigned*)H;      // 64 uints per row

    int sr0 = tid >> 2, sq0 = tid & 3;
    int sr1 = (tid + 512) >> 2, sq1 = tid & 3;
    int g0 = blockIdx.x * 256 + sr0; g0 = g0 < n ? g0 : n - 1;
    int g1 = blockIdx.x * 256 + sr1; g1 = g1 < n ? g1 : n - 1;

    uint4 pf0, pf1;
    #define G2_LOAD(ks) {                                                     \
        pf0 = *(const uint4*)&Hu[(size_t)g0 * 64 + (ks) * 16 + sq0 * 4];      \
        pf1 = *(const uint4*)&Hu[(size_t)g1 * 64 + (ks) * 16 + sq1 * 4]; }
    #define G2_WRITE(buf) {                                                   \
        *(uint4*)&xs[buf][sr0 * LP + sq0 * 4] = pf0;                          \
        *(uint4*)&xs[buf][sr1 * LP + sq1 * 4] = pf1; }

    f32x4 acc[4][2];
    #pragma unroll
    for (int m = 0; m < 4; ++m)
        #pragma unroll
        for (int nn = 0; nn < 2; ++nn) acc[m][nn] = (f32x4){0.f, 0.f, 0.f, 0.f};

    G2_LOAD(0);
    G2_WRITE(0);
    G2_LOAD(1);
    __syncthreads();

    #pragma unroll
    for (int ks = 0; ks < NS; ++ks) {
        int cur = ks & 1;
        if (ks + 1 < NS) G2_WRITE(cur ^ 1);
        if (ks + 2 < NS) G2_LOAD(ks + 2);
        F8 a[4], b[2];
        #pragma unroll
        for (int m = 0; m < 4; ++m)
            a[m].q = *(const uint4*)&xs[cur][(wm * 64 + m * 16 + la) * LP + lb * 4];
        #pragma unroll
        for (int nn = 0; nn < 2; ++nn) {
            int col = colbase + nn * 16 + la;
            b[nn].q = *(const uint4*)(Wt + (size_t)col * K + ks * 32 + lb * 8);
        }
        #pragma unroll
        for (int m = 0; m < 4; ++m)
            #pragma unroll
            for (int nn = 0; nn < 2; ++nn)
                acc[m][nn] = __builtin_amdgcn_mfma_f32_16x16x32_bf16(
                    a[m].v, b[nn].v, acc[m][nn], 0, 0, 0);
        __syncthreads();
    }
    #undef G2_LOAD
    #undef G2_WRITE

    #pragma unroll
    for (int m = 0; m < 4; ++m) {
        int r0 = rowbase + m * 16 + lb * 4;
        float dv[4];
        #pragma unroll
        for (int r = 0; r < 4; ++r) dv[r] = (r0 + r < n) ? dis[r0 + r] : 0.f;
        #pragma unroll
        for (int nn = 0; nn < 2; ++nn) {
            int col = colbase + nn * 16 + la;
            #pragma unroll
            for (int r = 0; r < 4; ++r) {
                int row = r0 + r;
                if (row < n)
                    G[(size_t)row * OUT_CH + col] = f2b(acc[m][nn][r] * dv[r]);
            }
        }
    }
}

// ---------------- Aggregation 1: h1 = bf16(relu(dis .* (self+gather) + b1)) --
// QUARTER-WAVE per edge: 16 lanes x uint4 = 256B row; 4 edges per wave-step,
// 4-deep unroll -> 16 gathers (4KB) in flight. Lane owns chans [8*hl, 8*hl+8).

__device__ inline void acc8(float* s, uint4 u) {
    float2 t;
    t = unpack_bf16(u.x); s[0] += t.x; s[1] += t.y;
    t = unpack_bf16(u.y); s[2] += t.x; s[3] += t.y;
    t = unpack_bf16(u.z); s[4] += t.x; s[5] += t.y;
    t = unpack_bf16(u.w); s[6] += t.x; s[7] += t.y;
}

__global__ __launch_bounds__(256) void agg1_kernel(
    const unsigned* __restrict__ G, const int* __restrict__ row_ptr,
    const int* __restrict__ csr_src, const float* __restrict__ dis,
    const float* __restrict__ b1, unsigned* __restrict__ H, int n) {
    int wid = (blockIdx.x * blockDim.x + threadIdx.x) >> 6;
    int lane = threadIdx.x & 63;
    if (wid >= n) return;
    int q = lane >> 4, hl = lane & 15;
    const char* Gb = (const char*)G;              // row = 256B
    unsigned lofs = (unsigned)(hl << 4);
    float s0[8] = {0,0,0,0,0,0,0,0}, s1[8] = {0,0,0,0,0,0,0,0};
    float s2[8] = {0,0,0,0,0,0,0,0}, s3[8] = {0,0,0,0,0,0,0,0};
    int beg = row_ptr[wid], end = row_ptr[wid + 1];
    for (int base = beg; base < end; base += 64) {
        int m = end - base; if (m > 64) m = 64;
        int idx = csr_src[base + (lane < m ? lane : m - 1)];
        int j = 0;
        for (; j + 16 <= m; j += 16) {
            unsigned o0 = ((unsigned)__shfl(idx, j +      q) << 8) + lofs;
            unsigned o1 = ((unsigned)__shfl(idx, j +  4 + q) << 8) + lofs;
            unsigned o2 = ((unsigned)__shfl(idx, j +  8 + q) << 8) + lofs;
            unsigned o3 = ((unsigned)__shfl(idx, j + 12 + q) << 8) + lofs;
            uint4 u0 = *(const uint4*)(Gb + o0);
            uint4 u1 = *(const uint4*)(Gb + o1);
            uint4 u2 = *(const uint4*)(Gb + o2);
            uint4 u3 = *(const uint4*)(Gb + o3);
            acc8(s0, u0); acc8(s1, u1); acc8(s2, u2); acc8(s3, u3);
        }
        for (; j + 4 <= m; j += 4) {
            unsigned o0 = ((unsigned)__shfl(idx, j + q) << 8) + lofs;
            uint4 u0 = *(const uint4*)(Gb + o0);
            acc8(s0, u0);
        }
        int rem = m - j;                          // 0..3
        if (rem) {
            int ii = __shfl(idx, j + (q < rem ? q : 0));
            if (q < rem) {
                uint4 u = *(const uint4*)(Gb + (((unsigned)ii << 8) + lofs));
                acc8(s0, u);
            }
        }
    }
    #pragma unroll
    for (int c = 0; c < 8; ++c) s0[c] += s1[c] + s2[c] + s3[c];
    #pragma unroll
    for (int c = 0; c < 8; ++c) {
        s0[c] += __shfl_xor(s0[c], 16);
        s0[c] += __shfl_xor(s0[c], 32);
    }
    uint4 su = *(const uint4*)(Gb + (((unsigned)wid << 8) + lofs));   // self
    acc8(s0, su);
    float d = dis[wid];
    float bb[8];
    *(float4*)&bb[0] = ((const float4*)b1)[hl * 2];
    *(float4*)&bb[4] = ((const float4*)b1)[hl * 2 + 1];
    float o[8];
    #pragma unroll
    for (int c = 0; c < 8; ++c) o[c] = fmaxf(fmaf(s0[c], d, bb[c]), 0.f);
    if (q == 0) {
        uint4 ou;
        ou.x = pack_bf16(o[0], o[1]);
        ou.y = pack_bf16(o[2], o[3]);
        ou.z = pack_bf16(o[4], o[5]);
        ou.w = pack_bf16(o[6], o[7]);
        *(uint4*)((char*)H + (((unsigned)wid << 8) + lofs)) = ou;
    }
}

// ---------------- Aggregation 2: out = dis .* (self+gather) + b2 -------------
// Quarter-wave: 16 lanes x uint2 = 128B row; lane owns chans [4*hl, 4*hl+4).

__device__ inline void acc4(float* s, uint2 u) {
    float2 t;
    t = unpack_bf16(u.x); s[0] += t.x; s[1] += t.y;
    t = unpack_bf16(u.y); s[2] += t.x; s[3] += t.y;
}

__global__ __launch_bounds__(256) void agg2_kernel(
    const unsigned short* __restrict__ G, const int* __restrict__ row_ptr,
    const int* __restrict__ csr_src, const float* __restrict__ dis,
    const float* __restrict__ b2, float* __restrict__ out, int n) {
    int wid = (blockIdx.x * blockDim.x + threadIdx.x) >> 6;
    int lane = threadIdx.x & 63;
    if (wid >= n) return;
    int q = lane >> 4, hl = lane & 15;
    const char* Gb = (const char*)G;              // row = 128B
    unsigned lofs = (unsigned)(hl << 3);
    float s0[4] = {0,0,0,0}, s1[4] = {0,0,0,0}, s2[4] = {0,0,0,0}, s3[4] = {0,0,0,0};
    int beg = row_ptr[wid], end = row_ptr[wid + 1];
    for (int base = beg; base < end; base += 64) {
        int m = end - base; if (m > 64) m = 64;
        int idx = csr_src[base + (lane < m ? lane : m - 1)];
        int j = 0;
        for (; j + 16 <= m; j += 16) {
            unsigned o0 = ((unsigned)__shfl(idx, j +      q) << 7) + lofs;
            unsigned o1 = ((unsigned)__shfl(idx, j +  4 + q) << 7) + lofs;
            unsigned o2 = ((unsigned)__shfl(idx, j +  8 + q) << 7) + lofs;
            unsigned o3 = ((unsigned)__shfl(idx, j + 12 + q) << 7) + lofs;
            uint2 u0 = *(const uint2*)(Gb + o0);
            uint2 u1 = *(const uint2*)(Gb + o1);
            uint2 u2 = *(const uint2*)(Gb + o2);
            uint2 u3 = *(const uint2*)(Gb + o3);
            acc4(s0, u0); acc4(s1, u1); acc4(s2, u2); acc4(s3, u3);
        }
        for (; j + 4 <= m; j += 4) {
            unsigned o0 = ((unsigned)__shfl(idx, j + q) << 7) + lofs;
            uint2 u0 = *(const uint2*)(Gb + o0);
            acc4(s0, u0);
        }
        int rem = m - j;
        if (rem) {
            int ii = __shfl(idx, j + (q < rem ? q : 0));
            if (q < rem) {
                uint2 u = *(const uint2*)(Gb + (((unsigned)ii << 7) + lofs));
                acc4(s0, u);
            }
        }
    }
    #pragma unroll
    for (int c = 0; c < 4; ++c) s0[c] += s1[c] + s2[c] + s3[c];
    #pragma unroll
    for (int c = 0; c < 4; ++c) {
        s0[c] += __shfl_xor(s0[c], 16);
        s0[c] += __shfl_xor(s0[c], 32);
    }
    uint2 su = *(const uint2*)(Gb + (((unsigned)wid << 7) + lofs));   // self
    acc4(s0, su);
    float d = dis[wid];
    float4 bb = ((const float4*)b2)[hl];
    if (q == 0) {
        float4 o;
        o.x = fmaf(s0[0], d, bb.x);
        o.y = fmaf(s0[1], d, bb.y);
        o.z = fmaf(s0[2], d, bb.z);
        o.w = fmaf(s0[3], d, bb.w);
        ((float4*)out)[(size_t)wid * 16 + hl] = o;
    }
}

// ---------------- launch ----------------

extern "C" void kernel_launch(void* const* d_in, const int* in_sizes, int n_in,
                              void* d_out, int out_size, void* d_ws, size_t ws_size,
                              hipStream_t stream) {
    const float* x  = (const float*)d_in[0];
    const int*   ei = (const int*)d_in[1];
    const float* W1 = (const float*)d_in[2];
    const float* b1 = (const float*)d_in[3];
    const float* W2 = (const float*)d_in[4];
    const float* b2 = (const float*)d_in[5];
    float* out = (float*)d_out;

    int n = in_sizes[0] / IN_CH;       // 100000
    int E = in_sizes[1] / 2;           // 1600000
    const int* srcv = ei;
    const int* dstv = ei + E;

    int NB    = (E + EPB - 1) / EPB;   // 391 edge-blocks
    int NBUCK = (n + 255) >> 8;        // 391 buckets (256 nodes each)
    int L     = NBUCK * NB;

    char* w = (char*)d_ws;
    unsigned short* g1 = (unsigned short*)w;  w += (size_t)n * HID * 2;   // 25.6 MB
    unsigned short* h1 = (unsigned short*)w;  w += (size_t)n * HID * 2;   // 25.6 MB
    unsigned short* g2 = g1;                                              // overlay
    unsigned short* wt1 = (unsigned short*)w; w += (size_t)IN_CH * HID * 2;
    unsigned short* wt2 = (unsigned short*)w; w += (size_t)HID * OUT_CH * 2;
    unsigned short* lrank = (unsigned short*)w; w += (size_t)E * 2;       // 3.2 MB
    int*      blockhist = (int*)w; w += (size_t)L * 4;
    int*      flatscan  = (int*)w; w += (size_t)(L + 1) * 4;
    int*      partial   = (int*)w; w += (size_t)1024 * 4;
    unsigned* sorted    = (unsigned*)w; w += (size_t)E * 4;               // 6.4 MB
    int*      csr       = (int*)w; w += (size_t)E * 4;                    // 6.4 MB
    int*      row_ptr   = (int*)w; w += (size_t)(n + 1) * 4;
    float*    dis       = (float*)w; w += (size_t)n * 4;

    int nb2 = (L + 255) / 256;

    bucket_hist<<<NB, 256, 0, stream>>>(dstv, lrank, blockhist, E, NB, NBUCK);
    scan_partial_kernel<<<nb2, 256, 0, stream>>>(blockhist, partial, L);
    scan_top_kernel<<<1, 1024, 0, stream>>>(partial, nb2, flatscan, L);
    scan_final_kernel<<<nb2, 256, 0, stream>>>(blockhist, partial, flatscan, L);
    bucket_scatter<<<NB, 256, 0, stream>>>(srcv, dstv, lrank, flatscan, sorted, E, NB);
    bucket_finalize<<<NBUCK, 256, 0, stream>>>(sorted, flatscan, csr, row_ptr, dis, NB, n);

    wt_kernel<<<(IN_CH * HID + 255) / 256, 256, 0, stream>>>(W1, wt1, IN_CH, HID);
    wt_kernel<<<(HID * OUT_CH + 255) / 256, 256, 0, stream>>>(W2, wt2, HID, OUT_CH);

    gemm1_mfma<<<(n + 255) / 256, 512, 0, stream>>>(x, wt1, dis, g1, n);
    agg1_kernel<<<(n + 3) / 4, 256, 0, stream>>>((const unsigned*)g1, row_ptr, csr, dis, b1, (unsigned*)h1, n);
    gemm2_mfma<<<(n + 255) / 256, 512, 0, stream>>>(h1, wt2, dis, g2, n);
    agg2_kernel<<<(n + 3) / 4, 256, 0, stream>>>(g2, row_ptr, csr, dis, b2, out, n);
}